// Round 4
// baseline (643.347 us; speedup 1.0000x reference)
//
#include <hip/hip_runtime.h>

// GATConv: N=50000, E=1600000, DIM_IN=256, HEADS=4, DIM_OUT=32 (HC=128)
// Pipeline: zero-cnt -> proj(x@W -> xp) -> att(a_src,a_dst) -> count -> scan -> scatter(CSR) -> aggregate
// No segment-max (softmax shift-invariant; scores bounded: |e| ~< 5 => exp <= ~150, fp32-safe).
// No fp32 atomics: CSR by dst, one wave per dst node accumulates in registers.
// All indirect indices bounds-guarded: garbage edge data cannot cause OOB access.

#define DIN 256
#define HC 128
#define NH 4
#define NEG 0.2f

// ---------------- init: zero the degree counters ----------------
__global__ void zero_kernel(int* __restrict__ p, int n) {
    int i = blockIdx.x * blockDim.x + threadIdx.x;
    if (i < n) p[i] = 0;
}

// ---------------- projection: xp = x @ W  (N x 256 @ 256 x 128) ----------------
// block 256 threads, 64 nodes/block. thread (ti,tj): ti=node-group(4 nodes), tj=channel-group(8 ch)
__global__ __launch_bounds__(256) void proj_kernel(const float* __restrict__ x,
                                                   const float* __restrict__ W,
                                                   float* __restrict__ xp, int n) {
    __shared__ float xs[64][33];    // 64 nodes x 32 k (+1 pad)
    __shared__ float Wl[32][128];   // k-tile x channels
    const int tid = threadIdx.x;
    const int ti = tid & 15;        // node group
    const int tj = tid >> 4;        // channel group (0..15) -> ch tj*8..tj*8+7
    const int node0 = blockIdx.x * 64;

    float acc[4][8];
#pragma unroll
    for (int j = 0; j < 4; ++j)
#pragma unroll
        for (int c = 0; c < 8; ++c) acc[j][c] = 0.f;

    for (int kt = 0; kt < DIN; kt += 32) {
        __syncthreads();
        // stage x tile: 64x32 = 2048 floats, 8 per thread, coalesced over k
#pragma unroll
        for (int r = 0; r < 8; ++r) {
            int idx = tid + r * 256;
            int nn = idx >> 5;
            int kk = idx & 31;
            int gn = node0 + nn;
            xs[nn][kk] = (gn < n) ? x[(size_t)gn * DIN + kt + kk] : 0.f;
        }
        // stage W tile: 32x128 = 4096 floats, 16 per thread, coalesced
#pragma unroll
        for (int r = 0; r < 16; ++r) {
            int idx = tid + r * 256;
            int kk = idx >> 7;
            int cc = idx & 127;
            Wl[kk][cc] = W[(size_t)(kt + kk) * HC + cc];
        }
        __syncthreads();
#pragma unroll 4
        for (int kk = 0; kk < 32; ++kk) {
            const float4 w0 = *(const float4*)&Wl[kk][tj * 8];
            const float4 w1 = *(const float4*)&Wl[kk][tj * 8 + 4];
#pragma unroll
            for (int j = 0; j < 4; ++j) {
                float xv = xs[ti * 4 + j][kk];
                acc[j][0] += xv * w0.x; acc[j][1] += xv * w0.y;
                acc[j][2] += xv * w0.z; acc[j][3] += xv * w0.w;
                acc[j][4] += xv * w1.x; acc[j][5] += xv * w1.y;
                acc[j][6] += xv * w1.z; acc[j][7] += xv * w1.w;
            }
        }
    }
#pragma unroll
    for (int j = 0; j < 4; ++j) {
        int node = node0 + ti * 4 + j;
        if (node < n) {
            float4 v0 = make_float4(acc[j][0], acc[j][1], acc[j][2], acc[j][3]);
            float4 v1 = make_float4(acc[j][4], acc[j][5], acc[j][6], acc[j][7]);
            *(float4*)&xp[(size_t)node * HC + tj * 8]     = v0;
            *(float4*)&xp[(size_t)node * HC + tj * 8 + 4] = v1;
        }
    }
}

// ---------------- per-node attention logits ----------------
// block 256 = 2 nodes x 128 channels; reduce 32-ch head groups via shuffle
__global__ __launch_bounds__(256) void att_kernel(const float* __restrict__ xp,
                                                  const float* __restrict__ attS,
                                                  const float* __restrict__ attD,
                                                  float* __restrict__ a_src,
                                                  float* __restrict__ a_dst, int n) {
    const int tid = threadIdx.x;
    const int node = blockIdx.x * 2 + (tid >> 7);
    if (node >= n) return;
    const int c = tid & 127;
    float v = xp[(size_t)node * HC + c];
    float ps = v * attS[c];
    float pd = v * attD[c];
#pragma unroll
    for (int s = 16; s >= 1; s >>= 1) {
        ps += __shfl_down(ps, s, 32);
        pd += __shfl_down(pd, s, 32);
    }
    if ((c & 31) == 0) {
        a_src[node * NH + (c >> 5)] = ps;
        a_dst[node * NH + (c >> 5)] = pd;
    }
}

// ---------------- CSR build ----------------
__global__ void count_kernel(const int* __restrict__ ei, int* __restrict__ cnt,
                             int e, int n) {
    int i = blockIdx.x * blockDim.x + threadIdx.x;
    if (i < e) {
        int dst = ei[e + i];
        if ((unsigned)dst < (unsigned)n) atomicAdd(&cnt[dst], 1);
    }
}

// single-block exclusive scan over cnt[0..n) -> off[0..n], plus cursor copy
__global__ __launch_bounds__(1024) void scan_kernel(const int* __restrict__ cnt,
                                                    int* __restrict__ off,
                                                    int* __restrict__ cur, int n) {
    __shared__ int buf[1024];
    __shared__ int carry;
    const int tid = threadIdx.x;
    if (tid == 0) carry = 0;
    __syncthreads();
    for (int base = 0; base < n; base += 1024) {
        int i = base + tid;
        int v = (i < n) ? cnt[i] : 0;
        buf[tid] = v;
        __syncthreads();
        for (int s = 1; s < 1024; s <<= 1) {
            int t = (tid >= s) ? buf[tid - s] : 0;
            __syncthreads();
            buf[tid] += t;
            __syncthreads();
        }
        int incl = buf[tid] + carry;
        int excl = incl - v;
        if (i < n) { off[i] = excl; cur[i] = excl; }
        __syncthreads();
        if (tid == 1023) carry = incl;
        __syncthreads();
    }
    if (tid == 0) off[n] = carry;
}

__global__ void scatter_kernel(const int* __restrict__ ei, int* __restrict__ cur,
                               int* __restrict__ srt, int e, int n) {
    int i = blockIdx.x * blockDim.x + threadIdx.x;
    if (i < e) {
        int src = ei[i];
        int dst = ei[e + i];
        if ((unsigned)dst < (unsigned)n && (unsigned)src < (unsigned)n) {
            int pos = atomicAdd(&cur[dst], 1);
            if ((unsigned)pos < (unsigned)e) srt[pos] = src;
        }
    }
}

// ---------------- aggregate: one wave per dst node ----------------
__global__ __launch_bounds__(256) void agg_kernel(const float* __restrict__ xp,
                                                  const float* __restrict__ a_src,
                                                  const float* __restrict__ a_dst,
                                                  const int* __restrict__ off,
                                                  const int* __restrict__ srt,
                                                  const float* __restrict__ bias,
                                                  float* __restrict__ out, int n, int e) {
    const int gwave = (blockIdx.x * blockDim.x + threadIdx.x) >> 6;
    if (gwave >= n) return;
    const int node = gwave;
    const int lane = threadIdx.x & 63;
    const int c0 = lane, c1 = lane + 64;
    const int h0 = lane >> 5, h1 = h0 + 2;

    const float ad0 = a_dst[node * NH + h0];
    const float ad1 = a_dst[node * NH + h1];

    // self loop
    float as0 = a_src[node * NH + h0];
    float as1 = a_src[node * NH + h1];
    float e0 = as0 + ad0; e0 = (e0 > 0.f) ? e0 : NEG * e0;
    float e1 = as1 + ad1; e1 = (e1 > 0.f) ? e1 : NEG * e1;
    float x0 = __expf(e0);
    float x1 = __expf(e1);
    float acc0 = x0 * xp[(size_t)node * HC + c0];
    float acc1 = x1 * xp[(size_t)node * HC + c1];
    float den0 = x0, den1 = x1;

    int kb = off[node];
    int ke = off[node + 1];
    // clamp against corrupted CSR state (defensive, branch-predictable)
    if (kb < 0) kb = 0;
    if (ke > e) ke = e;
#pragma unroll 2
    for (int k = kb; k < ke; ++k) {
        int s = srt[k];
        if ((unsigned)s >= (unsigned)n) continue;
        float s0 = a_src[s * NH + h0];
        float s1 = a_src[s * NH + h1];
        float f0 = s0 + ad0; f0 = (f0 > 0.f) ? f0 : NEG * f0;
        float f1 = s1 + ad1; f1 = (f1 > 0.f) ? f1 : NEG * f1;
        float g0 = __expf(f0);
        float g1 = __expf(f1);
        acc0 += g0 * xp[(size_t)s * HC + c0];
        acc1 += g1 * xp[(size_t)s * HC + c1];
        den0 += g0; den1 += g1;
    }
    out[(size_t)node * HC + c0] = acc0 / den0 + bias[c0];
    out[(size_t)node * HC + c1] = acc1 / den1 + bias[c1];
}

// ---------------- launch ----------------
extern "C" void kernel_launch(void* const* d_in, const int* in_sizes, int n_in,
                              void* d_out, int out_size, void* d_ws, size_t ws_size,
                              hipStream_t stream) {
    if (n_in < 6 || !d_out || !d_ws) return;   // defensive: malformed harness call
    const float* x    = (const float*)d_in[0];
    const int*   ei   = (const int*)d_in[1];   // [2, E] int
    const float* W    = (const float*)d_in[2];
    const float* attS = (const float*)d_in[3];
    const float* attD = (const float*)d_in[4];
    const float* bias = (const float*)d_in[5];
    float* out = (float*)d_out;

    const int N = in_sizes[0] / DIN;
    const int E = in_sizes[1] / 2;
    if (N <= 0 || E <= 0) return;              // defensive: zero-dim grid launch

    // workspace carve (256B aligned)
    char* ws = (char*)d_ws;
    size_t off_b = 0;
    auto carve = [&](size_t bytes) {
        size_t p = off_b;
        off_b = (off_b + bytes + 255) & ~(size_t)255;
        return (void*)(ws + p);
    };
    float* xp    = (float*)carve((size_t)N * HC * 4);
    float* a_src = (float*)carve((size_t)N * NH * 4);
    float* a_dst = (float*)carve((size_t)N * NH * 4);
    int*   cnt   = (int*)carve((size_t)N * 4);
    int*   offp  = (int*)carve((size_t)(N + 1) * 4);
    int*   cur   = (int*)carve((size_t)N * 4);
    int*   srt   = (int*)carve((size_t)E * 4);
    (void)out_size;
    if (off_b > ws_size) return;  // defensive: never write OOB scratch

    zero_kernel<<<(N + 255) / 256, 256, 0, stream>>>(cnt, N);
    proj_kernel<<<(N + 63) / 64, 256, 0, stream>>>(x, W, xp, N);
    att_kernel<<<(N + 1) / 2, 256, 0, stream>>>(xp, attS, attD, a_src, a_dst, N);
    count_kernel<<<(E + 255) / 256, 256, 0, stream>>>(ei, cnt, E, N);
    scan_kernel<<<1, 1024, 0, stream>>>(cnt, offp, cur, N);
    scatter_kernel<<<(E + 255) / 256, 256, 0, stream>>>(ei, cur, srt, E, N);
    agg_kernel<<<(N * 64 + 255) / 256, 256, 0, stream>>>(xp, a_src, a_dst, offp, srt,
                                                         bias, out, N, E);
}

// Round 5
// 472.419 us; speedup vs baseline: 1.3618x; 1.3618x over previous
//
#include <hip/hip_runtime.h>

// GATConv: N=50000, E=1600000, DIM_IN=256, HEADS=4, DIM_OUT=32 (HC=128)
// R5: multi-block scan (was single-block serial), att fused into proj epilogue,
//     agg restructured: float2/lane (1 head/lane), 4-wide batched edge loop for MLP.

#define DIN 256
#define HC 128
#define NH 4
#define NEG 0.2f

// ---------------- init: zero the degree counters ----------------
__global__ void zero_kernel(int* __restrict__ p, int n) {
    int i = blockIdx.x * blockDim.x + threadIdx.x;
    if (i < n) p[i] = 0;
}

// ---------------- projection + fused attention logits ----------------
// xp = x @ W  (N x 256 @ 256 x 128); epilogue computes a_src/a_dst via LDS reduction.
// block 256 threads, 64 nodes/block. thread (ti,tj): ti=node-group(4 nodes), tj=channel-group(8 ch)
__global__ __launch_bounds__(256) void proj_kernel(const float* __restrict__ x,
                                                   const float* __restrict__ W,
                                                   const float* __restrict__ attS,
                                                   const float* __restrict__ attD,
                                                   float* __restrict__ xp,
                                                   float* __restrict__ a_src,
                                                   float* __restrict__ a_dst, int n) {
    __shared__ float xs[64][33];    // 64 nodes x 32 k (+1 pad)
    __shared__ float Wl[32][128];   // k-tile x channels
    __shared__ float psL[64][17];   // per-node per-tj partial dots (att_src)
    __shared__ float pdL[64][17];   // (att_dst)
    const int tid = threadIdx.x;
    const int ti = tid & 15;        // node group
    const int tj = tid >> 4;        // channel group (0..15) -> ch tj*8..tj*8+7
    const int node0 = blockIdx.x * 64;

    float acc[4][8];
#pragma unroll
    for (int j = 0; j < 4; ++j)
#pragma unroll
        for (int c = 0; c < 8; ++c) acc[j][c] = 0.f;

    for (int kt = 0; kt < DIN; kt += 32) {
        __syncthreads();
        // stage x tile: 64x32 = 2048 floats, 8 per thread, coalesced over k
#pragma unroll
        for (int r = 0; r < 8; ++r) {
            int idx = tid + r * 256;
            int nn = idx >> 5;
            int kk = idx & 31;
            int gn = node0 + nn;
            xs[nn][kk] = (gn < n) ? x[(size_t)gn * DIN + kt + kk] : 0.f;
        }
        // stage W tile: 32x128 = 4096 floats, 16 per thread, coalesced
#pragma unroll
        for (int r = 0; r < 16; ++r) {
            int idx = tid + r * 256;
            int kk = idx >> 7;
            int cc = idx & 127;
            Wl[kk][cc] = W[(size_t)(kt + kk) * HC + cc];
        }
        __syncthreads();
#pragma unroll 4
        for (int kk = 0; kk < 32; ++kk) {
            const float4 w0 = *(const float4*)&Wl[kk][tj * 8];
            const float4 w1 = *(const float4*)&Wl[kk][tj * 8 + 4];
#pragma unroll
            for (int j = 0; j < 4; ++j) {
                float xv = xs[ti * 4 + j][kk];
                acc[j][0] += xv * w0.x; acc[j][1] += xv * w0.y;
                acc[j][2] += xv * w0.z; acc[j][3] += xv * w0.w;
                acc[j][4] += xv * w1.x; acc[j][5] += xv * w1.y;
                acc[j][6] += xv * w1.z; acc[j][7] += xv * w1.w;
            }
        }
    }
    // store xp + att partials
    float as[8], ad[8];
#pragma unroll
    for (int c = 0; c < 8; ++c) {
        as[c] = attS[tj * 8 + c];
        ad[c] = attD[tj * 8 + c];
    }
#pragma unroll
    for (int j = 0; j < 4; ++j) {
        int node = node0 + ti * 4 + j;
        float ps = 0.f, pd = 0.f;
#pragma unroll
        for (int c = 0; c < 8; ++c) { ps += acc[j][c] * as[c]; pd += acc[j][c] * ad[c]; }
        psL[ti * 4 + j][tj] = ps;
        pdL[ti * 4 + j][tj] = pd;
        if (node < n) {
            float4 v0 = make_float4(acc[j][0], acc[j][1], acc[j][2], acc[j][3]);
            float4 v1 = make_float4(acc[j][4], acc[j][5], acc[j][6], acc[j][7]);
            *(float4*)&xp[(size_t)node * HC + tj * 8]     = v0;
            *(float4*)&xp[(size_t)node * HC + tj * 8 + 4] = v1;
        }
    }
    __syncthreads();
    // reduce: thread t -> (node_local = t>>2, head = t&3); head h covers tj 4h..4h+3
    {
        int nl = tid >> 2;
        int h  = tid & 3;
        int node = node0 + nl;
        if (node < n) {
            float s = psL[nl][h * 4] + psL[nl][h * 4 + 1] + psL[nl][h * 4 + 2] + psL[nl][h * 4 + 3];
            float d = pdL[nl][h * 4] + pdL[nl][h * 4 + 1] + pdL[nl][h * 4 + 2] + pdL[nl][h * 4 + 3];
            a_src[node * NH + h] = s;
            a_dst[node * NH + h] = d;
        }
    }
}

// ---------------- CSR build ----------------
__global__ void count_kernel(const int* __restrict__ ei, int* __restrict__ cnt,
                             int e, int n) {
    int i = blockIdx.x * blockDim.x + threadIdx.x;
    if (i < e) {
        int dst = ei[e + i];
        if ((unsigned)dst < (unsigned)n) atomicAdd(&cnt[dst], 1);
    }
}

// pass 1: per-block exclusive scan of 1024-chunks; emit block sums
__global__ __launch_bounds__(1024) void scan1_kernel(const int* __restrict__ cnt,
                                                     int* __restrict__ partial,
                                                     int* __restrict__ bsum, int n) {
    __shared__ int buf[1024];
    const int tid = threadIdx.x;
    const int i = blockIdx.x * 1024 + tid;
    int v = (i < n) ? cnt[i] : 0;
    buf[tid] = v;
    __syncthreads();
    for (int s = 1; s < 1024; s <<= 1) {
        int t = (tid >= s) ? buf[tid - s] : 0;
        __syncthreads();
        buf[tid] += t;
        __syncthreads();
    }
    if (i < n) partial[i] = buf[tid] - v;   // exclusive within chunk
    if (tid == 1023) bsum[blockIdx.x] = buf[tid];
}

// pass 2: one wave scans the block sums (nb <= 64); bsum -> exclusive; off[n] = total
__global__ __launch_bounds__(64) void scan2_kernel(int* __restrict__ bsum, int nb,
                                                   int* __restrict__ off, int n) {
    const int lane = threadIdx.x;
    int v = (lane < nb) ? bsum[lane] : 0;
    const int orig = v;
#pragma unroll
    for (int s = 1; s < 64; s <<= 1) {
        int t = __shfl_up(v, s, 64);
        if (lane >= s) v += t;
    }
    if (lane < nb) bsum[lane] = v - orig;   // exclusive block offset
    if (lane == nb - 1) off[n] = v;         // grand total
}

// pass 3: add block offsets -> final off + cursor copy
__global__ void scan3_kernel(const int* __restrict__ partial, const int* __restrict__ bsum,
                             int* __restrict__ off, int* __restrict__ cur, int n) {
    int i = blockIdx.x * blockDim.x + threadIdx.x;
    if (i < n) {
        int o = partial[i] + bsum[i >> 10];
        off[i] = o;
        cur[i] = o;
    }
}

__global__ void scatter_kernel(const int* __restrict__ ei, int* __restrict__ cur,
                               int* __restrict__ srt, int e, int n) {
    int i = blockIdx.x * blockDim.x + threadIdx.x;
    if (i < e) {
        int src = ei[i];
        int dst = ei[e + i];
        if ((unsigned)dst < (unsigned)n && (unsigned)src < (unsigned)n) {
            int pos = atomicAdd(&cur[dst], 1);
            if ((unsigned)pos < (unsigned)e) srt[pos] = src;
        }
    }
}

// ---------------- aggregate: one wave per dst node ----------------
// lane owns channels {2*lane, 2*lane+1} (one head: h = lane>>4); 4-wide batched edge loop.
__global__ __launch_bounds__(256) void agg_kernel(const float* __restrict__ xp,
                                                  const float* __restrict__ a_src,
                                                  const float* __restrict__ a_dst,
                                                  const int* __restrict__ off,
                                                  const int* __restrict__ srt,
                                                  const float* __restrict__ bias,
                                                  float* __restrict__ out, int n) {
    const int gwave = (blockIdx.x * blockDim.x + threadIdx.x) >> 6;
    if (gwave >= n) return;
    const int node = gwave;
    const int lane = threadIdx.x & 63;
    const int h = lane >> 4;                   // (2*lane)>>5
    const float2* __restrict__ xp2 = (const float2*)xp;

    const float ad = a_dst[node * NH + h];

    // self loop
    float e0 = a_src[node * NH + h] + ad;
    e0 = (e0 > 0.f) ? e0 : NEG * e0;
    float g = __expf(e0);
    float2 v = xp2[(size_t)node * 64 + lane];
    float accx = g * v.x, accy = g * v.y, den = g;

    const int kb = off[node];
    const int ke = off[node + 1];
    int k = kb;
    for (; k + 4 <= ke; k += 4) {
        const int s0 = srt[k], s1 = srt[k + 1], s2 = srt[k + 2], s3 = srt[k + 3];
        float f0 = a_src[s0 * NH + h] + ad;
        float f1 = a_src[s1 * NH + h] + ad;
        float f2 = a_src[s2 * NH + h] + ad;
        float f3 = a_src[s3 * NH + h] + ad;
        f0 = (f0 > 0.f) ? f0 : NEG * f0;
        f1 = (f1 > 0.f) ? f1 : NEG * f1;
        f2 = (f2 > 0.f) ? f2 : NEG * f2;
        f3 = (f3 > 0.f) ? f3 : NEG * f3;
        const float g0 = __expf(f0), g1 = __expf(f1), g2 = __expf(f2), g3 = __expf(f3);
        const float2 v0 = xp2[(size_t)s0 * 64 + lane];
        const float2 v1 = xp2[(size_t)s1 * 64 + lane];
        const float2 v2 = xp2[(size_t)s2 * 64 + lane];
        const float2 v3 = xp2[(size_t)s3 * 64 + lane];
        accx += g0 * v0.x + g1 * v1.x + g2 * v2.x + g3 * v3.x;
        accy += g0 * v0.y + g1 * v1.y + g2 * v2.y + g3 * v3.y;
        den  += g0 + g1 + g2 + g3;
    }
    for (; k < ke; ++k) {
        const int s = srt[k];
        float f = a_src[s * NH + h] + ad;
        f = (f > 0.f) ? f : NEG * f;
        const float gg = __expf(f);
        const float2 vv = xp2[(size_t)s * 64 + lane];
        accx += gg * vv.x;
        accy += gg * vv.y;
        den  += gg;
    }
    const float2 b2 = ((const float2*)bias)[lane];
    float2 o;
    const float inv = 1.0f / den;
    o.x = accx * inv + b2.x;
    o.y = accy * inv + b2.y;
    ((float2*)out)[(size_t)node * 64 + lane] = o;
}

// ---------------- launch ----------------
extern "C" void kernel_launch(void* const* d_in, const int* in_sizes, int n_in,
                              void* d_out, int out_size, void* d_ws, size_t ws_size,
                              hipStream_t stream) {
    if (n_in < 6 || !d_out || !d_ws) return;
    const float* x    = (const float*)d_in[0];
    const int*   ei   = (const int*)d_in[1];   // [2, E] int32 (verified by passing R4)
    const float* W    = (const float*)d_in[2];
    const float* attS = (const float*)d_in[3];
    const float* attD = (const float*)d_in[4];
    const float* bias = (const float*)d_in[5];
    float* out = (float*)d_out;

    const int N = in_sizes[0] / DIN;
    const int E = in_sizes[1] / 2;
    if (N <= 0 || E <= 0) return;
    const int NB = (N + 1023) / 1024;          // scan blocks (49 for N=50000)
    if (NB > 64) return;                        // scan2 is single-wave; N<=65536 supported

    // workspace carve (256B aligned)
    char* ws = (char*)d_ws;
    size_t off_b = 0;
    auto carve = [&](size_t bytes) {
        size_t p = off_b;
        off_b = (off_b + bytes + 255) & ~(size_t)255;
        return (void*)(ws + p);
    };
    float* xp    = (float*)carve((size_t)N * HC * 4);
    float* a_src = (float*)carve((size_t)N * NH * 4);
    float* a_dst = (float*)carve((size_t)N * NH * 4);
    int*   cnt   = (int*)carve((size_t)N * 4);
    int*   part  = (int*)carve((size_t)N * 4);
    int*   bsum  = (int*)carve(64 * 4);
    int*   offp  = (int*)carve((size_t)(N + 1) * 4);
    int*   cur   = (int*)carve((size_t)N * 4);
    int*   srt   = (int*)carve((size_t)E * 4);
    (void)out_size;
    if (off_b > ws_size) return;

    zero_kernel<<<(N + 255) / 256, 256, 0, stream>>>(cnt, N);
    proj_kernel<<<(N + 63) / 64, 256, 0, stream>>>(x, W, attS, attD, xp, a_src, a_dst, N);
    count_kernel<<<(E + 255) / 256, 256, 0, stream>>>(ei, cnt, E, N);
    scan1_kernel<<<NB, 1024, 0, stream>>>(cnt, part, bsum, N);
    scan2_kernel<<<1, 64, 0, stream>>>(bsum, NB, offp, N);
    scan3_kernel<<<(N + 255) / 256, 256, 0, stream>>>(part, bsum, offp, cur, N);
    scatter_kernel<<<(E + 255) / 256, 256, 0, stream>>>(ei, cur, srt, E, N);
    agg_kernel<<<(N * 64 + 255) / 256, 256, 0, stream>>>(xp, a_src, a_dst, offp, srt,
                                                         bias, out, N);
}

// Round 6
// 341.466 us; speedup vs baseline: 1.8841x; 1.3835x over previous
//
#include <hip/hip_runtime.h>

// GATConv: N=50000, E=1600000, DIM_IN=256, HEADS=4, DIM_OUT=32 (HC=128)
// R6: CSR build rewritten as 2-level counting sort (bucket = 256 nodes):
//   hist -> bscan -> bin (packed 4B/edge, register-held, run-reserved writes)
//   -> csr (per-bucket LDS counting sort; srt writes confined to 33KB L2-hot region).
// Replaces count+scan123+scatter whose random 4B stores cost 64B HBM writeback each
// (measured WRITE_SIZE 100MB for a 6.4MB buffer, 130us latency-bound).

#define DIN 256
#define HC 128
#define NH 4
#define NEG 0.2f
#define BSH 8
#define BSZ 256   // nodes per bucket

// ---------------- zero small arrays ----------------
__global__ void zero_kernel(int* __restrict__ p, int n) {
    int i = blockIdx.x * blockDim.x + threadIdx.x;
    if (i < n) p[i] = 0;
}

// ---------------- projection + fused attention logits ----------------
__global__ __launch_bounds__(256) void proj_kernel(const float* __restrict__ x,
                                                   const float* __restrict__ W,
                                                   const float* __restrict__ attS,
                                                   const float* __restrict__ attD,
                                                   float* __restrict__ xp,
                                                   float* __restrict__ a_src,
                                                   float* __restrict__ a_dst, int n) {
    __shared__ float xs[64][33];
    __shared__ float Wl[32][128];
    __shared__ float psL[64][17];
    __shared__ float pdL[64][17];
    const int tid = threadIdx.x;
    const int ti = tid & 15;
    const int tj = tid >> 4;
    const int node0 = blockIdx.x * 64;

    float acc[4][8];
#pragma unroll
    for (int j = 0; j < 4; ++j)
#pragma unroll
        for (int c = 0; c < 8; ++c) acc[j][c] = 0.f;

    for (int kt = 0; kt < DIN; kt += 32) {
        __syncthreads();
#pragma unroll
        for (int r = 0; r < 8; ++r) {
            int idx = tid + r * 256;
            int nn = idx >> 5;
            int kk = idx & 31;
            int gn = node0 + nn;
            xs[nn][kk] = (gn < n) ? x[(size_t)gn * DIN + kt + kk] : 0.f;
        }
#pragma unroll
        for (int r = 0; r < 16; ++r) {
            int idx = tid + r * 256;
            int kk = idx >> 7;
            int cc = idx & 127;
            Wl[kk][cc] = W[(size_t)(kt + kk) * HC + cc];
        }
        __syncthreads();
#pragma unroll 4
        for (int kk = 0; kk < 32; ++kk) {
            const float4 w0 = *(const float4*)&Wl[kk][tj * 8];
            const float4 w1 = *(const float4*)&Wl[kk][tj * 8 + 4];
#pragma unroll
            for (int j = 0; j < 4; ++j) {
                float xv = xs[ti * 4 + j][kk];
                acc[j][0] += xv * w0.x; acc[j][1] += xv * w0.y;
                acc[j][2] += xv * w0.z; acc[j][3] += xv * w0.w;
                acc[j][4] += xv * w1.x; acc[j][5] += xv * w1.y;
                acc[j][6] += xv * w1.z; acc[j][7] += xv * w1.w;
            }
        }
    }
    float as[8], ad[8];
#pragma unroll
    for (int c = 0; c < 8; ++c) {
        as[c] = attS[tj * 8 + c];
        ad[c] = attD[tj * 8 + c];
    }
#pragma unroll
    for (int j = 0; j < 4; ++j) {
        int node = node0 + ti * 4 + j;
        float ps = 0.f, pd = 0.f;
#pragma unroll
        for (int c = 0; c < 8; ++c) { ps += acc[j][c] * as[c]; pd += acc[j][c] * ad[c]; }
        psL[ti * 4 + j][tj] = ps;
        pdL[ti * 4 + j][tj] = pd;
        if (node < n) {
            float4 v0 = make_float4(acc[j][0], acc[j][1], acc[j][2], acc[j][3]);
            float4 v1 = make_float4(acc[j][4], acc[j][5], acc[j][6], acc[j][7]);
            *(float4*)&xp[(size_t)node * HC + tj * 8]     = v0;
            *(float4*)&xp[(size_t)node * HC + tj * 8 + 4] = v1;
        }
    }
    __syncthreads();
    {
        int nl = tid >> 2;
        int h  = tid & 3;
        int node = node0 + nl;
        if (node < n) {
            float s = psL[nl][h * 4] + psL[nl][h * 4 + 1] + psL[nl][h * 4 + 2] + psL[nl][h * 4 + 3];
            float d = pdL[nl][h * 4] + pdL[nl][h * 4 + 1] + pdL[nl][h * 4 + 2] + pdL[nl][h * 4 + 3];
            a_src[node * NH + h] = s;
            a_dst[node * NH + h] = d;
        }
    }
}

// ---------------- CSR build: two-level counting sort ----------------
// pass 1: bucket histogram (LDS-privatized)
__global__ __launch_bounds__(256) void hist_kernel(const int* __restrict__ ei,
                                                   int* __restrict__ ghist, int e, int n) {
    __shared__ int h[256];
    const int tid = threadIdx.x;
    h[tid] = 0;
    __syncthreads();
    const int base = blockIdx.x * 4096;
#pragma unroll
    for (int j = 0; j < 16; ++j) {
        int i = base + j * 256 + tid;
        if (i < e) {
            int src = ei[i];
            int dst = ei[e + i];
            if ((unsigned)dst < (unsigned)n && (unsigned)src < (unsigned)n)
                atomicAdd(&h[dst >> BSH], 1);
        }
    }
    __syncthreads();
    if (h[tid]) atomicAdd(&ghist[tid], h[tid]);
}

// pass 2: one block scans bucket sums -> bases + cursors
__global__ __launch_bounds__(256) void bscan_kernel(const int* __restrict__ ghist,
                                                    int* __restrict__ gbase,
                                                    int* __restrict__ gcur, int nbuck) {
    __shared__ int buf[256];
    const int tid = threadIdx.x;
    int v = (tid < nbuck) ? ghist[tid] : 0;
    buf[tid] = v;
    __syncthreads();
    for (int s = 1; s < 256; s <<= 1) {
        int t = (tid >= s) ? buf[tid - s] : 0;
        __syncthreads();
        buf[tid] += t;
        __syncthreads();
    }
    int excl = buf[tid] - v;
    if (tid < nbuck) { gbase[tid] = excl; gcur[tid] = excl; }
    if (tid == nbuck - 1) gbase[nbuck] = buf[tid];
}

// pass 3: bin edges into bucket runs; packed (dst&255)<<24 | src (4B/edge)
__global__ __launch_bounds__(256) void bin_kernel(const int* __restrict__ ei,
                                                  int* __restrict__ gcur,
                                                  unsigned* __restrict__ binned,
                                                  int e, int n) {
    __shared__ int h[256];
    __shared__ int rbase[256];
    const int tid = threadIdx.x;
    h[tid] = 0;
    __syncthreads();
    const int base = blockIdx.x * 4096;
    unsigned pk[16];
    int bk[16];
#pragma unroll
    for (int j = 0; j < 16; ++j) {
        int i = base + j * 256 + tid;
        bk[j] = -1;
        if (i < e) {
            int src = ei[i];
            int dst = ei[e + i];
            if ((unsigned)dst < (unsigned)n && (unsigned)src < (unsigned)n) {
                bk[j] = dst >> BSH;
                pk[j] = ((unsigned)(dst & (BSZ - 1)) << 24) | (unsigned)src;
                atomicAdd(&h[bk[j]], 1);
            }
        }
    }
    __syncthreads();
    if (h[tid]) rbase[tid] = atomicAdd(&gcur[tid], h[tid]);
    h[tid] = 0;   // reuse as local cursor (owner-thread ordered: rbase read precedes reset)
    __syncthreads();
#pragma unroll
    for (int j = 0; j < 16; ++j) {
        if (bk[j] >= 0) {
            int p = atomicAdd(&h[bk[j]], 1);
            binned[rbase[bk[j]] + p] = pk[j];
        }
    }
}

// pass 4: per-bucket local counting sort -> off[] + srt[] (writes confined to ~33KB region)
__global__ __launch_bounds__(256) void csr_kernel(const unsigned* __restrict__ binned,
                                                  const int* __restrict__ gbase,
                                                  int* __restrict__ off,
                                                  int* __restrict__ srt,
                                                  int n, int nbuck) {
    __shared__ int cnt[256], buf[256], cur[256];
    const int tid = threadIdx.x;
    const int b = blockIdx.x;
    const int kb = gbase[b];
    const int ke = gbase[b + 1];
    cnt[tid] = 0;
    __syncthreads();
    for (int i = kb + tid; i < ke; i += 256)
        atomicAdd(&cnt[binned[i] >> 24], 1);
    __syncthreads();
    int v = cnt[tid];
    buf[tid] = v;
    __syncthreads();
    for (int s = 1; s < 256; s <<= 1) {
        int t = (tid >= s) ? buf[tid - s] : 0;
        __syncthreads();
        buf[tid] += t;
        __syncthreads();
    }
    const int excl = kb + buf[tid] - v;
    const int node = b * BSZ + tid;
    if (node < n) off[node] = excl;
    if (tid == 0 && b == nbuck - 1) off[n] = ke;
    cur[tid] = excl;
    __syncthreads();
    for (int i = kb + tid; i < ke; i += 256) {
        unsigned pv = binned[i];
        int nl = pv >> 24;
        int pos = atomicAdd(&cur[nl], 1);
        srt[pos] = (int)(pv & 0xFFFFFFu);
    }
}

// ---------------- aggregate: one wave per dst node ----------------
__global__ __launch_bounds__(256) void agg_kernel(const float* __restrict__ xp,
                                                  const float* __restrict__ a_src,
                                                  const float* __restrict__ a_dst,
                                                  const int* __restrict__ off,
                                                  const int* __restrict__ srt,
                                                  const float* __restrict__ bias,
                                                  float* __restrict__ out, int n) {
    const int gwave = (blockIdx.x * blockDim.x + threadIdx.x) >> 6;
    if (gwave >= n) return;
    const int node = gwave;
    const int lane = threadIdx.x & 63;
    const int h = lane >> 4;
    const float2* __restrict__ xp2 = (const float2*)xp;

    const float ad = a_dst[node * NH + h];

    float e0 = a_src[node * NH + h] + ad;
    e0 = (e0 > 0.f) ? e0 : NEG * e0;
    float g = __expf(e0);
    float2 v = xp2[(size_t)node * 64 + lane];
    float accx = g * v.x, accy = g * v.y, den = g;

    const int kb = off[node];
    const int ke = off[node + 1];
    int k = kb;
    for (; k + 4 <= ke; k += 4) {
        const int s0 = srt[k], s1 = srt[k + 1], s2 = srt[k + 2], s3 = srt[k + 3];
        float f0 = a_src[s0 * NH + h] + ad;
        float f1 = a_src[s1 * NH + h] + ad;
        float f2 = a_src[s2 * NH + h] + ad;
        float f3 = a_src[s3 * NH + h] + ad;
        f0 = (f0 > 0.f) ? f0 : NEG * f0;
        f1 = (f1 > 0.f) ? f1 : NEG * f1;
        f2 = (f2 > 0.f) ? f2 : NEG * f2;
        f3 = (f3 > 0.f) ? f3 : NEG * f3;
        const float g0 = __expf(f0), g1 = __expf(f1), g2 = __expf(f2), g3 = __expf(f3);
        const float2 v0 = xp2[(size_t)s0 * 64 + lane];
        const float2 v1 = xp2[(size_t)s1 * 64 + lane];
        const float2 v2 = xp2[(size_t)s2 * 64 + lane];
        const float2 v3 = xp2[(size_t)s3 * 64 + lane];
        accx += g0 * v0.x + g1 * v1.x + g2 * v2.x + g3 * v3.x;
        accy += g0 * v0.y + g1 * v1.y + g2 * v2.y + g3 * v3.y;
        den  += g0 + g1 + g2 + g3;
    }
    for (; k < ke; ++k) {
        const int s = srt[k];
        float f = a_src[s * NH + h] + ad;
        f = (f > 0.f) ? f : NEG * f;
        const float gg = __expf(f);
        const float2 vv = xp2[(size_t)s * 64 + lane];
        accx += gg * vv.x;
        accy += gg * vv.y;
        den  += gg;
    }
    const float2 b2 = ((const float2*)bias)[lane];
    float2 o;
    const float inv = 1.0f / den;
    o.x = accx * inv + b2.x;
    o.y = accy * inv + b2.y;
    ((float2*)out)[(size_t)node * 64 + lane] = o;
}

// ---------------- launch ----------------
extern "C" void kernel_launch(void* const* d_in, const int* in_sizes, int n_in,
                              void* d_out, int out_size, void* d_ws, size_t ws_size,
                              hipStream_t stream) {
    if (n_in < 6 || !d_out || !d_ws) return;
    const float* x    = (const float*)d_in[0];
    const int*   ei   = (const int*)d_in[1];
    const float* W    = (const float*)d_in[2];
    const float* attS = (const float*)d_in[3];
    const float* attD = (const float*)d_in[4];
    const float* bias = (const float*)d_in[5];
    float* out = (float*)d_out;

    const int N = in_sizes[0] / DIN;
    const int E = in_sizes[1] / 2;
    if (N <= 0 || E <= 0) return;
    const int NBUCK = (N + BSZ - 1) >> BSH;
    if (NBUCK > 256 || N > (1 << 24)) return;  // csr/bin packing limits (N<=65536 here)

    char* ws = (char*)d_ws;
    size_t off_b = 0;
    auto carve = [&](size_t bytes) {
        size_t p = off_b;
        off_b = (off_b + bytes + 255) & ~(size_t)255;
        return (void*)(ws + p);
    };
    float*    xp     = (float*)carve((size_t)N * HC * 4);
    float*    a_src  = (float*)carve((size_t)N * NH * 4);
    float*    a_dst  = (float*)carve((size_t)N * NH * 4);
    int*      ghist  = (int*)carve(257 * 4);
    int*      gbase  = (int*)carve(257 * 4);
    int*      gcur   = (int*)carve(257 * 4);
    unsigned* binned = (unsigned*)carve((size_t)E * 4);
    int*      offp   = (int*)carve((size_t)(N + 1) * 4);
    int*      srt    = (int*)carve((size_t)E * 4);
    (void)out_size;
    if (off_b > ws_size) return;

    const int ECH = (E + 4095) / 4096;

    zero_kernel<<<2, 256, 0, stream>>>(ghist, 257);
    proj_kernel<<<(N + 63) / 64, 256, 0, stream>>>(x, W, attS, attD, xp, a_src, a_dst, N);
    hist_kernel<<<ECH, 256, 0, stream>>>(ei, ghist, E, N);
    bscan_kernel<<<1, 256, 0, stream>>>(ghist, gbase, gcur, NBUCK);
    bin_kernel<<<ECH, 256, 0, stream>>>(ei, gcur, binned, E, N);
    csr_kernel<<<NBUCK, 256, 0, stream>>>(binned, gbase, offp, srt, N, NBUCK);
    agg_kernel<<<(N * 64 + 255) / 256, 256, 0, stream>>>(xp, a_src, a_dst, offp, srt,
                                                         bias, out, N);
}

// Round 7
// 341.383 us; speedup vs baseline: 1.8845x; 1.0002x over previous
//
#include <hip/hip_runtime.h>

// GATConv: N=50000, E=1600000, DIM_IN=256, HEADS=4, DIM_OUT=32 (HC=128)
// R7: agg edge loop 4-wide -> 8-wide batching (double the in-flight xp gathers per wave;
//     agg is latency-bound: R5->R6 dur scaled with concurrency at constant FETCH_SIZE).
// CSR build: 2-level counting sort (hist -> bscan -> bin -> csr), unchanged from R6.

#define DIN 256
#define HC 128
#define NH 4
#define NEG 0.2f
#define BSH 8
#define BSZ 256   // nodes per bucket

// ---------------- zero small arrays ----------------
__global__ void zero_kernel(int* __restrict__ p, int n) {
    int i = blockIdx.x * blockDim.x + threadIdx.x;
    if (i < n) p[i] = 0;
}

// ---------------- projection + fused attention logits ----------------
__global__ __launch_bounds__(256) void proj_kernel(const float* __restrict__ x,
                                                   const float* __restrict__ W,
                                                   const float* __restrict__ attS,
                                                   const float* __restrict__ attD,
                                                   float* __restrict__ xp,
                                                   float* __restrict__ a_src,
                                                   float* __restrict__ a_dst, int n) {
    __shared__ float xs[64][33];
    __shared__ float Wl[32][128];
    __shared__ float psL[64][17];
    __shared__ float pdL[64][17];
    const int tid = threadIdx.x;
    const int ti = tid & 15;
    const int tj = tid >> 4;
    const int node0 = blockIdx.x * 64;

    float acc[4][8];
#pragma unroll
    for (int j = 0; j < 4; ++j)
#pragma unroll
        for (int c = 0; c < 8; ++c) acc[j][c] = 0.f;

    for (int kt = 0; kt < DIN; kt += 32) {
        __syncthreads();
#pragma unroll
        for (int r = 0; r < 8; ++r) {
            int idx = tid + r * 256;
            int nn = idx >> 5;
            int kk = idx & 31;
            int gn = node0 + nn;
            xs[nn][kk] = (gn < n) ? x[(size_t)gn * DIN + kt + kk] : 0.f;
        }
#pragma unroll
        for (int r = 0; r < 16; ++r) {
            int idx = tid + r * 256;
            int kk = idx >> 7;
            int cc = idx & 127;
            Wl[kk][cc] = W[(size_t)(kt + kk) * HC + cc];
        }
        __syncthreads();
#pragma unroll 4
        for (int kk = 0; kk < 32; ++kk) {
            const float4 w0 = *(const float4*)&Wl[kk][tj * 8];
            const float4 w1 = *(const float4*)&Wl[kk][tj * 8 + 4];
#pragma unroll
            for (int j = 0; j < 4; ++j) {
                float xv = xs[ti * 4 + j][kk];
                acc[j][0] += xv * w0.x; acc[j][1] += xv * w0.y;
                acc[j][2] += xv * w0.z; acc[j][3] += xv * w0.w;
                acc[j][4] += xv * w1.x; acc[j][5] += xv * w1.y;
                acc[j][6] += xv * w1.z; acc[j][7] += xv * w1.w;
            }
        }
    }
    float as[8], ad[8];
#pragma unroll
    for (int c = 0; c < 8; ++c) {
        as[c] = attS[tj * 8 + c];
        ad[c] = attD[tj * 8 + c];
    }
#pragma unroll
    for (int j = 0; j < 4; ++j) {
        int node = node0 + ti * 4 + j;
        float ps = 0.f, pd = 0.f;
#pragma unroll
        for (int c = 0; c < 8; ++c) { ps += acc[j][c] * as[c]; pd += acc[j][c] * ad[c]; }
        psL[ti * 4 + j][tj] = ps;
        pdL[ti * 4 + j][tj] = pd;
        if (node < n) {
            float4 v0 = make_float4(acc[j][0], acc[j][1], acc[j][2], acc[j][3]);
            float4 v1 = make_float4(acc[j][4], acc[j][5], acc[j][6], acc[j][7]);
            *(float4*)&xp[(size_t)node * HC + tj * 8]     = v0;
            *(float4*)&xp[(size_t)node * HC + tj * 8 + 4] = v1;
        }
    }
    __syncthreads();
    {
        int nl = tid >> 2;
        int h  = tid & 3;
        int node = node0 + nl;
        if (node < n) {
            float s = psL[nl][h * 4] + psL[nl][h * 4 + 1] + psL[nl][h * 4 + 2] + psL[nl][h * 4 + 3];
            float d = pdL[nl][h * 4] + pdL[nl][h * 4 + 1] + pdL[nl][h * 4 + 2] + pdL[nl][h * 4 + 3];
            a_src[node * NH + h] = s;
            a_dst[node * NH + h] = d;
        }
    }
}

// ---------------- CSR build: two-level counting sort ----------------
__global__ __launch_bounds__(256) void hist_kernel(const int* __restrict__ ei,
                                                   int* __restrict__ ghist, int e, int n) {
    __shared__ int h[256];
    const int tid = threadIdx.x;
    h[tid] = 0;
    __syncthreads();
    const int base = blockIdx.x * 4096;
#pragma unroll
    for (int j = 0; j < 16; ++j) {
        int i = base + j * 256 + tid;
        if (i < e) {
            int src = ei[i];
            int dst = ei[e + i];
            if ((unsigned)dst < (unsigned)n && (unsigned)src < (unsigned)n)
                atomicAdd(&h[dst >> BSH], 1);
        }
    }
    __syncthreads();
    if (h[tid]) atomicAdd(&ghist[tid], h[tid]);
}

__global__ __launch_bounds__(256) void bscan_kernel(const int* __restrict__ ghist,
                                                    int* __restrict__ gbase,
                                                    int* __restrict__ gcur, int nbuck) {
    __shared__ int buf[256];
    const int tid = threadIdx.x;
    int v = (tid < nbuck) ? ghist[tid] : 0;
    buf[tid] = v;
    __syncthreads();
    for (int s = 1; s < 256; s <<= 1) {
        int t = (tid >= s) ? buf[tid - s] : 0;
        __syncthreads();
        buf[tid] += t;
        __syncthreads();
    }
    int excl = buf[tid] - v;
    if (tid < nbuck) { gbase[tid] = excl; gcur[tid] = excl; }
    if (tid == nbuck - 1) gbase[nbuck] = buf[tid];
}

__global__ __launch_bounds__(256) void bin_kernel(const int* __restrict__ ei,
                                                  int* __restrict__ gcur,
                                                  unsigned* __restrict__ binned,
                                                  int e, int n) {
    __shared__ int h[256];
    __shared__ int rbase[256];
    const int tid = threadIdx.x;
    h[tid] = 0;
    __syncthreads();
    const int base = blockIdx.x * 4096;
    unsigned pk[16];
    int bk[16];
#pragma unroll
    for (int j = 0; j < 16; ++j) {
        int i = base + j * 256 + tid;
        bk[j] = -1;
        if (i < e) {
            int src = ei[i];
            int dst = ei[e + i];
            if ((unsigned)dst < (unsigned)n && (unsigned)src < (unsigned)n) {
                bk[j] = dst >> BSH;
                pk[j] = ((unsigned)(dst & (BSZ - 1)) << 24) | (unsigned)src;
                atomicAdd(&h[bk[j]], 1);
            }
        }
    }
    __syncthreads();
    if (h[tid]) rbase[tid] = atomicAdd(&gcur[tid], h[tid]);
    h[tid] = 0;
    __syncthreads();
#pragma unroll
    for (int j = 0; j < 16; ++j) {
        if (bk[j] >= 0) {
            int p = atomicAdd(&h[bk[j]], 1);
            binned[rbase[bk[j]] + p] = pk[j];
        }
    }
}

__global__ __launch_bounds__(256) void csr_kernel(const unsigned* __restrict__ binned,
                                                  const int* __restrict__ gbase,
                                                  int* __restrict__ off,
                                                  int* __restrict__ srt,
                                                  int n, int nbuck) {
    __shared__ int cnt[256], buf[256], cur[256];
    const int tid = threadIdx.x;
    const int b = blockIdx.x;
    const int kb = gbase[b];
    const int ke = gbase[b + 1];
    cnt[tid] = 0;
    __syncthreads();
    for (int i = kb + tid; i < ke; i += 256)
        atomicAdd(&cnt[binned[i] >> 24], 1);
    __syncthreads();
    int v = cnt[tid];
    buf[tid] = v;
    __syncthreads();
    for (int s = 1; s < 256; s <<= 1) {
        int t = (tid >= s) ? buf[tid - s] : 0;
        __syncthreads();
        buf[tid] += t;
        __syncthreads();
    }
    const int excl = kb + buf[tid] - v;
    const int node = b * BSZ + tid;
    if (node < n) off[node] = excl;
    if (tid == 0 && b == nbuck - 1) off[n] = ke;
    cur[tid] = excl;
    __syncthreads();
    for (int i = kb + tid; i < ke; i += 256) {
        unsigned pv = binned[i];
        int nl = pv >> 24;
        int pos = atomicAdd(&cur[nl], 1);
        srt[pos] = (int)(pv & 0xFFFFFFu);
    }
}

// ---------------- aggregate: one wave per dst node, 8-wide batched edge loop ----------------
__global__ __launch_bounds__(256) void agg_kernel(const float* __restrict__ xp,
                                                  const float* __restrict__ a_src,
                                                  const float* __restrict__ a_dst,
                                                  const int* __restrict__ off,
                                                  const int* __restrict__ srt,
                                                  const float* __restrict__ bias,
                                                  float* __restrict__ out, int n) {
    const int gwave = (blockIdx.x * blockDim.x + threadIdx.x) >> 6;
    if (gwave >= n) return;
    const int node = gwave;
    const int lane = threadIdx.x & 63;
    const int h = lane >> 4;
    const float2* __restrict__ xp2 = (const float2*)xp;

    const float ad = a_dst[node * NH + h];

    // self loop
    float e0 = a_src[node * NH + h] + ad;
    e0 = (e0 > 0.f) ? e0 : NEG * e0;
    float g = __expf(e0);
    float2 v = xp2[(size_t)node * 64 + lane];
    float accx = g * v.x, accy = g * v.y, den = g;

    const int kb = off[node];
    const int ke = off[node + 1];
    int k = kb;
    for (; k + 8 <= ke; k += 8) {
        int s[8];
#pragma unroll
        for (int j = 0; j < 8; ++j) s[j] = srt[k + j];
        float f[8];
#pragma unroll
        for (int j = 0; j < 8; ++j) f[j] = a_src[s[j] * NH + h];
        float2 vv[8];
#pragma unroll
        for (int j = 0; j < 8; ++j) vv[j] = xp2[(size_t)s[j] * 64 + lane];
#pragma unroll
        for (int j = 0; j < 8; ++j) {
            float t = f[j] + ad;
            t = (t > 0.f) ? t : NEG * t;
            const float gg = __expf(t);
            accx += gg * vv[j].x;
            accy += gg * vv[j].y;
            den  += gg;
        }
    }
    for (; k + 4 <= ke; k += 4) {
        int s[4];
#pragma unroll
        for (int j = 0; j < 4; ++j) s[j] = srt[k + j];
        float f[4];
#pragma unroll
        for (int j = 0; j < 4; ++j) f[j] = a_src[s[j] * NH + h];
        float2 vv[4];
#pragma unroll
        for (int j = 0; j < 4; ++j) vv[j] = xp2[(size_t)s[j] * 64 + lane];
#pragma unroll
        for (int j = 0; j < 4; ++j) {
            float t = f[j] + ad;
            t = (t > 0.f) ? t : NEG * t;
            const float gg = __expf(t);
            accx += gg * vv[j].x;
            accy += gg * vv[j].y;
            den  += gg;
        }
    }
    for (; k < ke; ++k) {
        const int s = srt[k];
        float f = a_src[s * NH + h] + ad;
        f = (f > 0.f) ? f : NEG * f;
        const float gg = __expf(f);
        const float2 vv = xp2[(size_t)s * 64 + lane];
        accx += gg * vv.x;
        accy += gg * vv.y;
        den  += gg;
    }
    const float2 b2 = ((const float2*)bias)[lane];
    float2 o;
    const float inv = 1.0f / den;
    o.x = accx * inv + b2.x;
    o.y = accy * inv + b2.y;
    ((float2*)out)[(size_t)node * 64 + lane] = o;
}

// ---------------- launch ----------------
extern "C" void kernel_launch(void* const* d_in, const int* in_sizes, int n_in,
                              void* d_out, int out_size, void* d_ws, size_t ws_size,
                              hipStream_t stream) {
    if (n_in < 6 || !d_out || !d_ws) return;
    const float* x    = (const float*)d_in[0];
    const int*   ei   = (const int*)d_in[1];
    const float* W    = (const float*)d_in[2];
    const float* attS = (const float*)d_in[3];
    const float* attD = (const float*)d_in[4];
    const float* bias = (const float*)d_in[5];
    float* out = (float*)d_out;

    const int N = in_sizes[0] / DIN;
    const int E = in_sizes[1] / 2;
    if (N <= 0 || E <= 0) return;
    const int NBUCK = (N + BSZ - 1) >> BSH;
    if (NBUCK > 256 || N > (1 << 24)) return;

    char* ws = (char*)d_ws;
    size_t off_b = 0;
    auto carve = [&](size_t bytes) {
        size_t p = off_b;
        off_b = (off_b + bytes + 255) & ~(size_t)255;
        return (void*)(ws + p);
    };
    float*    xp     = (float*)carve((size_t)N * HC * 4);
    float*    a_src  = (float*)carve((size_t)N * NH * 4);
    float*    a_dst  = (float*)carve((size_t)N * NH * 4);
    int*      ghist  = (int*)carve(257 * 4);
    int*      gbase  = (int*)carve(257 * 4);
    int*      gcur   = (int*)carve(257 * 4);
    unsigned* binned = (unsigned*)carve((size_t)E * 4);
    int*      offp   = (int*)carve((size_t)(N + 1) * 4);
    int*      srt    = (int*)carve((size_t)E * 4);
    (void)out_size;
    if (off_b > ws_size) return;

    const int ECH = (E + 4095) / 4096;

    zero_kernel<<<2, 256, 0, stream>>>(ghist, 257);
    proj_kernel<<<(N + 63) / 64, 256, 0, stream>>>(x, W, attS, attD, xp, a_src, a_dst, N);
    hist_kernel<<<ECH, 256, 0, stream>>>(ei, ghist, E, N);
    bscan_kernel<<<1, 256, 0, stream>>>(ghist, gbase, gcur, NBUCK);
    bin_kernel<<<ECH, 256, 0, stream>>>(ei, gcur, binned, E, N);
    csr_kernel<<<NBUCK, 256, 0, stream>>>(binned, gbase, offp, srt, N, NBUCK);
    agg_kernel<<<(N * 64 + 255) / 256, 256, 0, stream>>>(xp, a_src, a_dst, offp, srt,
                                                         bias, out, N);
}

// Round 8
// 296.890 us; speedup vs baseline: 2.1670x; 1.1499x over previous
//
#include <hip/hip_runtime.h>
#include <hip/hip_fp16.h>

// GATConv: N=50000, E=1600000, DIM_IN=256, HEADS=4, DIM_OUT=32 (HC=128)
// R8: agg is MSHR-limited (R7: 2x per-wave MLP + -13% occupancy = neutral) ->
//     cut cache-line requests per edge ~5 -> ~2.3:
//     (a) fp16 feature mirror xph (row 512B->256B, 4->2 lines); fp32 xp dropped entirely;
//     (b) edge scores exp(leaky(.)) precomputed in csr_kernel -> escore fp16[E*4];
//         agg loses the random a_src gather and the expf dependency chain.

#define DIN 256
#define HC 128
#define NH 4
#define NEG 0.2f
#define BSH 8
#define BSZ 256   // nodes per bucket

// ---------------- zero small arrays ----------------
__global__ void zero_kernel(int* __restrict__ p, int n) {
    int i = blockIdx.x * blockDim.x + threadIdx.x;
    if (i < n) p[i] = 0;
}

// ---------------- projection + fused attention logits (fp16 feature output) ----------------
__global__ __launch_bounds__(256) void proj_kernel(const float* __restrict__ x,
                                                   const float* __restrict__ W,
                                                   const float* __restrict__ attS,
                                                   const float* __restrict__ attD,
                                                   __half* __restrict__ xph,
                                                   float* __restrict__ a_src,
                                                   float* __restrict__ a_dst, int n) {
    __shared__ float xs[64][33];
    __shared__ float Wl[32][128];
    __shared__ float psL[64][17];
    __shared__ float pdL[64][17];
    const int tid = threadIdx.x;
    const int ti = tid & 15;
    const int tj = tid >> 4;
    const int node0 = blockIdx.x * 64;

    float acc[4][8];
#pragma unroll
    for (int j = 0; j < 4; ++j)
#pragma unroll
        for (int c = 0; c < 8; ++c) acc[j][c] = 0.f;

    for (int kt = 0; kt < DIN; kt += 32) {
        __syncthreads();
#pragma unroll
        for (int r = 0; r < 8; ++r) {
            int idx = tid + r * 256;
            int nn = idx >> 5;
            int kk = idx & 31;
            int gn = node0 + nn;
            xs[nn][kk] = (gn < n) ? x[(size_t)gn * DIN + kt + kk] : 0.f;
        }
#pragma unroll
        for (int r = 0; r < 16; ++r) {
            int idx = tid + r * 256;
            int kk = idx >> 7;
            int cc = idx & 127;
            Wl[kk][cc] = W[(size_t)(kt + kk) * HC + cc];
        }
        __syncthreads();
#pragma unroll 4
        for (int kk = 0; kk < 32; ++kk) {
            const float4 w0 = *(const float4*)&Wl[kk][tj * 8];
            const float4 w1 = *(const float4*)&Wl[kk][tj * 8 + 4];
#pragma unroll
            for (int j = 0; j < 4; ++j) {
                float xv = xs[ti * 4 + j][kk];
                acc[j][0] += xv * w0.x; acc[j][1] += xv * w0.y;
                acc[j][2] += xv * w0.z; acc[j][3] += xv * w0.w;
                acc[j][4] += xv * w1.x; acc[j][5] += xv * w1.y;
                acc[j][6] += xv * w1.z; acc[j][7] += xv * w1.w;
            }
        }
    }
    float as[8], ad[8];
#pragma unroll
    for (int c = 0; c < 8; ++c) {
        as[c] = attS[tj * 8 + c];
        ad[c] = attD[tj * 8 + c];
    }
#pragma unroll
    for (int j = 0; j < 4; ++j) {
        int node = node0 + ti * 4 + j;
        float ps = 0.f, pd = 0.f;
#pragma unroll
        for (int c = 0; c < 8; ++c) { ps += acc[j][c] * as[c]; pd += acc[j][c] * ad[c]; }
        psL[ti * 4 + j][tj] = ps;
        pdL[ti * 4 + j][tj] = pd;
        if (node < n) {
            __half2* xr = (__half2*)&xph[(size_t)node * HC];
            xr[tj * 4 + 0] = __floats2half2_rn(acc[j][0], acc[j][1]);
            xr[tj * 4 + 1] = __floats2half2_rn(acc[j][2], acc[j][3]);
            xr[tj * 4 + 2] = __floats2half2_rn(acc[j][4], acc[j][5]);
            xr[tj * 4 + 3] = __floats2half2_rn(acc[j][6], acc[j][7]);
        }
    }
    __syncthreads();
    {
        int nl = tid >> 2;
        int h  = tid & 3;
        int node = node0 + nl;
        if (node < n) {
            float s = psL[nl][h * 4] + psL[nl][h * 4 + 1] + psL[nl][h * 4 + 2] + psL[nl][h * 4 + 3];
            float d = pdL[nl][h * 4] + pdL[nl][h * 4 + 1] + pdL[nl][h * 4 + 2] + pdL[nl][h * 4 + 3];
            a_src[node * NH + h] = s;
            a_dst[node * NH + h] = d;
        }
    }
}

// ---------------- CSR build: two-level counting sort ----------------
__global__ __launch_bounds__(256) void hist_kernel(const int* __restrict__ ei,
                                                   int* __restrict__ ghist, int e, int n) {
    __shared__ int h[256];
    const int tid = threadIdx.x;
    h[tid] = 0;
    __syncthreads();
    const int base = blockIdx.x * 4096;
#pragma unroll
    for (int j = 0; j < 16; ++j) {
        int i = base + j * 256 + tid;
        if (i < e) {
            int src = ei[i];
            int dst = ei[e + i];
            if ((unsigned)dst < (unsigned)n && (unsigned)src < (unsigned)n)
                atomicAdd(&h[dst >> BSH], 1);
        }
    }
    __syncthreads();
    if (h[tid]) atomicAdd(&ghist[tid], h[tid]);
}

__global__ __launch_bounds__(256) void bscan_kernel(const int* __restrict__ ghist,
                                                    int* __restrict__ gbase,
                                                    int* __restrict__ gcur, int nbuck) {
    __shared__ int buf[256];
    const int tid = threadIdx.x;
    int v = (tid < nbuck) ? ghist[tid] : 0;
    buf[tid] = v;
    __syncthreads();
    for (int s = 1; s < 256; s <<= 1) {
        int t = (tid >= s) ? buf[tid - s] : 0;
        __syncthreads();
        buf[tid] += t;
        __syncthreads();
    }
    int excl = buf[tid] - v;
    if (tid < nbuck) { gbase[tid] = excl; gcur[tid] = excl; }
    if (tid == nbuck - 1) gbase[nbuck] = buf[tid];
}

__global__ __launch_bounds__(256) void bin_kernel(const int* __restrict__ ei,
                                                  int* __restrict__ gcur,
                                                  unsigned* __restrict__ binned,
                                                  int e, int n) {
    __shared__ int h[256];
    __shared__ int rbase[256];
    const int tid = threadIdx.x;
    h[tid] = 0;
    __syncthreads();
    const int base = blockIdx.x * 4096;
    unsigned pk[16];
    int bk[16];
#pragma unroll
    for (int j = 0; j < 16; ++j) {
        int i = base + j * 256 + tid;
        bk[j] = -1;
        if (i < e) {
            int src = ei[i];
            int dst = ei[e + i];
            if ((unsigned)dst < (unsigned)n && (unsigned)src < (unsigned)n) {
                bk[j] = dst >> BSH;
                pk[j] = ((unsigned)(dst & (BSZ - 1)) << 24) | (unsigned)src;
                atomicAdd(&h[bk[j]], 1);
            }
        }
    }
    __syncthreads();
    if (h[tid]) rbase[tid] = atomicAdd(&gcur[tid], h[tid]);
    h[tid] = 0;
    __syncthreads();
#pragma unroll
    for (int j = 0; j < 16; ++j) {
        if (bk[j] >= 0) {
            int p = atomicAdd(&h[bk[j]], 1);
            binned[rbase[bk[j]] + p] = pk[j];
        }
    }
}

// per-bucket local counting sort -> off[] + srt[] + fp16 edge scores
__global__ __launch_bounds__(256) void csr_kernel(const unsigned* __restrict__ binned,
                                                  const int* __restrict__ gbase,
                                                  const float* __restrict__ a_src,
                                                  const float* __restrict__ a_dst,
                                                  int* __restrict__ off,
                                                  int* __restrict__ srt,
                                                  __half* __restrict__ escore,
                                                  int n, int nbuck) {
    __shared__ int cnt[256], buf[256], cur[256];
    __shared__ float adL[BSZ * 4];     // bucket's a_dst rows (4 KB)
    const int tid = threadIdx.x;
    const int b = blockIdx.x;
    const int kb = gbase[b];
    const int ke = gbase[b + 1];
    cnt[tid] = 0;
    // stage a_dst (node-major -> contiguous per bucket)
#pragma unroll
    for (int r = 0; r < 4; ++r) {
        int idx = tid + r * 256;
        int gi = b * (BSZ * 4) + idx;
        adL[idx] = (gi < n * 4) ? a_dst[gi] : 0.f;
    }
    __syncthreads();
    for (int i = kb + tid; i < ke; i += 256)
        atomicAdd(&cnt[binned[i] >> 24], 1);
    __syncthreads();
    int v = cnt[tid];
    buf[tid] = v;
    __syncthreads();
    for (int s = 1; s < 256; s <<= 1) {
        int t = (tid >= s) ? buf[tid - s] : 0;
        __syncthreads();
        buf[tid] += t;
        __syncthreads();
    }
    const int excl = kb + buf[tid] - v;
    const int node = b * BSZ + tid;
    if (node < n) off[node] = excl;
    if (tid == 0 && b == nbuck - 1) off[n] = ke;
    cur[tid] = excl;
    __syncthreads();
    for (int i = kb + tid; i < ke; i += 256) {
        unsigned pv = binned[i];
        int nl = pv >> 24;
        int src = (int)(pv & 0xFFFFFFu);
        int pos = atomicAdd(&cur[nl], 1);
        srt[pos] = src;
        const float4 asv = *(const float4*)&a_src[(size_t)src * 4];
        float t0 = asv.x + adL[nl * 4 + 0]; t0 = (t0 > 0.f) ? t0 : NEG * t0;
        float t1 = asv.y + adL[nl * 4 + 1]; t1 = (t1 > 0.f) ? t1 : NEG * t1;
        float t2 = asv.z + adL[nl * 4 + 2]; t2 = (t2 > 0.f) ? t2 : NEG * t2;
        float t3 = asv.w + adL[nl * 4 + 3]; t3 = (t3 > 0.f) ? t3 : NEG * t3;
        __half2* ep = (__half2*)&escore[(size_t)pos * 4];
        ep[0] = __floats2half2_rn(__expf(t0), __expf(t1));
        ep[1] = __floats2half2_rn(__expf(t2), __expf(t3));
    }
}

// ---------------- aggregate: one wave per dst node, 8-wide batched edge loop ----------------
__global__ __launch_bounds__(256) void agg_kernel(const __half2* __restrict__ xh2,
                                                  const float* __restrict__ a_src,
                                                  const float* __restrict__ a_dst,
                                                  const int* __restrict__ off,
                                                  const int* __restrict__ srt,
                                                  const __half* __restrict__ escore,
                                                  const float* __restrict__ bias,
                                                  float* __restrict__ out, int n) {
    const int gwave = (blockIdx.x * blockDim.x + threadIdx.x) >> 6;
    if (gwave >= n) return;
    const int node = gwave;
    const int lane = threadIdx.x & 63;
    const int h = lane >> 4;

    // self loop (fp32 logits, fp16 feature row)
    float e0 = a_src[node * NH + h] + a_dst[node * NH + h];
    e0 = (e0 > 0.f) ? e0 : NEG * e0;
    float g = __expf(e0);
    float2 v = __half22float2(xh2[(size_t)node * 64 + lane]);
    float accx = g * v.x, accy = g * v.y, den = g;

    const int kb = off[node];
    const int ke = off[node + 1];
    int k = kb;
    for (; k + 8 <= ke; k += 8) {
        int s[8];
#pragma unroll
        for (int j = 0; j < 8; ++j) s[j] = srt[k + j];
        float sc[8];
#pragma unroll
        for (int j = 0; j < 8; ++j) sc[j] = __half2float(escore[(size_t)(k + j) * 4 + h]);
        __half2 hv[8];
#pragma unroll
        for (int j = 0; j < 8; ++j) hv[j] = xh2[(size_t)s[j] * 64 + lane];
#pragma unroll
        for (int j = 0; j < 8; ++j) {
            float2 vf = __half22float2(hv[j]);
            accx += sc[j] * vf.x;
            accy += sc[j] * vf.y;
            den  += sc[j];
        }
    }
    for (; k < ke; ++k) {
        const int s = srt[k];
        const float sc = __half2float(escore[(size_t)k * 4 + h]);
        const float2 vf = __half22float2(xh2[(size_t)s * 64 + lane]);
        accx += sc * vf.x;
        accy += sc * vf.y;
        den  += sc;
    }
    const float2 b2 = ((const float2*)bias)[lane];
    const float inv = 1.0f / den;
    float2 o;
    o.x = accx * inv + b2.x;
    o.y = accy * inv + b2.y;
    ((float2*)out)[(size_t)node * 64 + lane] = o;
}

// ---------------- launch ----------------
extern "C" void kernel_launch(void* const* d_in, const int* in_sizes, int n_in,
                              void* d_out, int out_size, void* d_ws, size_t ws_size,
                              hipStream_t stream) {
    if (n_in < 6 || !d_out || !d_ws) return;
    const float* x    = (const float*)d_in[0];
    const int*   ei   = (const int*)d_in[1];
    const float* W    = (const float*)d_in[2];
    const float* attS = (const float*)d_in[3];
    const float* attD = (const float*)d_in[4];
    const float* bias = (const float*)d_in[5];
    float* out = (float*)d_out;

    const int N = in_sizes[0] / DIN;
    const int E = in_sizes[1] / 2;
    if (N <= 0 || E <= 0) return;
    const int NBUCK = (N + BSZ - 1) >> BSH;
    if (NBUCK > 256 || N > (1 << 24)) return;

    char* ws = (char*)d_ws;
    size_t off_b = 0;
    auto carve = [&](size_t bytes) {
        size_t p = off_b;
        off_b = (off_b + bytes + 255) & ~(size_t)255;
        return (void*)(ws + p);
    };
    __half*   xph    = (__half*)carve((size_t)N * HC * 2);
    float*    a_src  = (float*)carve((size_t)N * NH * 4);
    float*    a_dst  = (float*)carve((size_t)N * NH * 4);
    int*      ghist  = (int*)carve(257 * 4);
    int*      gbase  = (int*)carve(257 * 4);
    int*      gcur   = (int*)carve(257 * 4);
    unsigned* binned = (unsigned*)carve((size_t)E * 4);
    int*      offp   = (int*)carve((size_t)(N + 1) * 4);
    int*      srt    = (int*)carve((size_t)E * 4);
    __half*   escore = (__half*)carve((size_t)E * NH * 2);
    (void)out_size;
    if (off_b > ws_size) return;

    const int ECH = (E + 4095) / 4096;

    zero_kernel<<<2, 256, 0, stream>>>(ghist, 257);
    proj_kernel<<<(N + 63) / 64, 256, 0, stream>>>(x, W, attS, attD, xph, a_src, a_dst, N);
    hist_kernel<<<ECH, 256, 0, stream>>>(ei, ghist, E, N);
    bscan_kernel<<<1, 256, 0, stream>>>(ghist, gbase, gcur, NBUCK);
    bin_kernel<<<ECH, 256, 0, stream>>>(ei, gcur, binned, E, N);
    csr_kernel<<<NBUCK, 256, 0, stream>>>(binned, gbase, a_src, a_dst, offp, srt,
                                          escore, N, NBUCK);
    agg_kernel<<<(N * 64 + 255) / 256, 256, 0, stream>>>((const __half2*)xph, a_src, a_dst,
                                                         offp, srt, escore, bias, out, N);
}

// Round 9
// 262.481 us; speedup vs baseline: 2.4510x; 1.1311x over previous
//
#include <hip/hip_runtime.h>
#include <hip/hip_fp16.h>

// GATConv: N=50000, E=1600000, DIM_IN=256, HEADS=4, DIM_OUT=32 (HC=128)
// R9: proj rewritten as f16 MFMA GEMM (v_mfma_f32_16x16x32_f16, fp32 acc).
//     wtrans pre-transposes W -> f16 Wt[128][256] once; proj stages x fp32->f16.
//     Old VALU proj was 83us at 31% VALUBusy / 25% occ / 4.9M LDS conflicts.
// CSR counting sort + fp16 gather agg unchanged from R8 (341->297us).

#define DIN 256
#define HC 128
#define NH 4
#define NEG 0.2f
#define BSH 8
#define BSZ 256

typedef _Float16 half8 __attribute__((ext_vector_type(8)));
typedef _Float16 half2v __attribute__((ext_vector_type(2)));
typedef float f32x4 __attribute__((ext_vector_type(4)));

// ---------------- zero small arrays ----------------
__global__ void zero_kernel(int* __restrict__ p, int n) {
    int i = blockIdx.x * blockDim.x + threadIdx.x;
    if (i < n) p[i] = 0;
}

// ---------------- W transpose + f16 convert: Wt[c][k] ----------------
__global__ __launch_bounds__(256) void wtrans_kernel(const float* __restrict__ W,
                                                     _Float16* __restrict__ Wt) {
    int i = blockIdx.x * 256 + threadIdx.x;   // 32768 = 256*128
    int k = i >> 7, c = i & 127;
    Wt[c * 256 + k] = (_Float16)W[i];
}

// ---------------- projection via MFMA + fused attention logits ----------------
// block: 64 nodes x 128 ch, 4 waves; wave w owns rows w*16..w*16+15.
// LDS: xs[64][40] f16 (staging) + Wl[128][40] f16; epilogue reuses as ep[64][136] f16.
__global__ __launch_bounds__(256) void proj_kernel(const float* __restrict__ x,
                                                   const _Float16* __restrict__ Wt,
                                                   const float* __restrict__ attS,
                                                   const float* __restrict__ attD,
                                                   __half* __restrict__ xph,
                                                   float* __restrict__ a_src,
                                                   float* __restrict__ a_dst, int n) {
    __shared__ _Float16 smem[8704];           // max(2560+5120 staging, 64*136 epilogue)
    __shared__ float attSL[128], attDL[128];
    _Float16* xs = smem;                      // [64][40]
    _Float16* Wl = smem + 2560;               // [128][40]
    _Float16* ep = smem;                      // [64][136]

    const int tid  = threadIdx.x;
    const int node0 = blockIdx.x * 64;
    const int wave = tid >> 6;
    const int lane = tid & 63;
    const int l15  = lane & 15;
    const int quad = lane >> 4;

    if (tid < 128) attSL[tid] = attS[tid];
    else           attDL[tid - 128] = attD[tid - 128];

    f32x4 acc[8];
#pragma unroll
    for (int ct = 0; ct < 8; ++ct) acc[ct] = (f32x4){0.f, 0.f, 0.f, 0.f};

    for (int kt = 0; kt < DIN; kt += 32) {
        __syncthreads();
        // stage x tile: 64 rows x 32 k, fp32 float2 -> packed half2 (conflict-free)
#pragma unroll
        for (int r = 0; r < 4; ++r) {
            int idx = tid + r * 256;
            int row = idx >> 4;
            int kp  = idx & 15;
            int gn = node0 + row;
            float2 xv = make_float2(0.f, 0.f);
            if (gn < n) xv = *(const float2*)&x[(size_t)gn * DIN + kt + kp * 2];
            half2v p; p[0] = (_Float16)xv.x; p[1] = (_Float16)xv.y;
            *(half2v*)&xs[row * 40 + kp * 2] = p;
        }
        // stage Wt tile: 128 rows x 32 k, contiguous 8-half chunks
#pragma unroll
        for (int r = 0; r < 2; ++r) {
            int id = tid + r * 256;
            int c = id >> 2;
            int q = id & 3;
            half8 wv = *(const half8*)&Wt[(size_t)c * 256 + kt + q * 8];
            *(half8*)&Wl[c * 40 + q * 8] = wv;
        }
        __syncthreads();
        // A frag: A[m=l15][k=quad*8+j]; B frag: B[n=l15][k=quad*8+j] (Wl is W^T)
        half8 af = *(const half8*)&xs[(wave * 16 + l15) * 40 + quad * 8];
#pragma unroll
        for (int ct = 0; ct < 8; ++ct) {
            half8 bf = *(const half8*)&Wl[(ct * 16 + l15) * 40 + quad * 8];
            acc[ct] = __builtin_amdgcn_mfma_f32_16x16x32_f16(af, bf, acc[ct], 0, 0, 0);
        }
    }
    __syncthreads();
    // C/D layout: col=lane&15, row=quad*4+reg -> ep[64][136]
#pragma unroll
    for (int ct = 0; ct < 8; ++ct)
#pragma unroll
        for (int r = 0; r < 4; ++r) {
            int row = wave * 16 + quad * 4 + r;
            ep[row * 136 + ct * 16 + l15] = (_Float16)acc[ct][r];
        }
    __syncthreads();
    // coalesced xph store: thread -> (row, 32-half chunk)
    {
        int row = tid >> 2, ch = tid & 3;
        int node = node0 + row;
        if (node < n) {
            const uint4* s = (const uint4*)&ep[row * 136 + ch * 32];
            uint4* d = (uint4*)&xph[(size_t)node * HC + ch * 32];
            d[0] = s[0]; d[1] = s[1]; d[2] = s[2]; d[3] = s[3];
        }
    }
    // attention logits from ep: thread -> (node_local, head)
    {
        int nl = tid >> 2, h = tid & 3;
        int node = node0 + nl;
        if (node < n) {
            float ps = 0.f, pd = 0.f;
            const _Float16* er = &ep[nl * 136 + h * 32];
#pragma unroll
            for (int c = 0; c < 32; ++c) {
                float v = (float)er[c];
                ps += v * attSL[h * 32 + c];
                pd += v * attDL[h * 32 + c];
            }
            a_src[node * NH + h] = ps;
            a_dst[node * NH + h] = pd;
        }
    }
}

// ---------------- CSR build: two-level counting sort ----------------
__global__ __launch_bounds__(256) void hist_kernel(const int* __restrict__ ei,
                                                   int* __restrict__ ghist, int e, int n) {
    __shared__ int h[256];
    const int tid = threadIdx.x;
    h[tid] = 0;
    __syncthreads();
    const int base = blockIdx.x * 4096;
#pragma unroll
    for (int j = 0; j < 16; ++j) {
        int i = base + j * 256 + tid;
        if (i < e) {
            int src = ei[i];
            int dst = ei[e + i];
            if ((unsigned)dst < (unsigned)n && (unsigned)src < (unsigned)n)
                atomicAdd(&h[dst >> BSH], 1);
        }
    }
    __syncthreads();
    if (h[tid]) atomicAdd(&ghist[tid], h[tid]);
}

__global__ __launch_bounds__(256) void bscan_kernel(const int* __restrict__ ghist,
                                                    int* __restrict__ gbase,
                                                    int* __restrict__ gcur, int nbuck) {
    __shared__ int buf[256];
    const int tid = threadIdx.x;
    int v = (tid < nbuck) ? ghist[tid] : 0;
    buf[tid] = v;
    __syncthreads();
    for (int s = 1; s < 256; s <<= 1) {
        int t = (tid >= s) ? buf[tid - s] : 0;
        __syncthreads();
        buf[tid] += t;
        __syncthreads();
    }
    int excl = buf[tid] - v;
    if (tid < nbuck) { gbase[tid] = excl; gcur[tid] = excl; }
    if (tid == nbuck - 1) gbase[nbuck] = buf[tid];
}

__global__ __launch_bounds__(256) void bin_kernel(const int* __restrict__ ei,
                                                  int* __restrict__ gcur,
                                                  unsigned* __restrict__ binned,
                                                  int e, int n) {
    __shared__ int h[256];
    __shared__ int rbase[256];
    const int tid = threadIdx.x;
    h[tid] = 0;
    __syncthreads();
    const int base = blockIdx.x * 4096;
    unsigned pk[16];
    int bk[16];
#pragma unroll
    for (int j = 0; j < 16; ++j) {
        int i = base + j * 256 + tid;
        bk[j] = -1;
        if (i < e) {
            int src = ei[i];
            int dst = ei[e + i];
            if ((unsigned)dst < (unsigned)n && (unsigned)src < (unsigned)n) {
                bk[j] = dst >> BSH;
                pk[j] = ((unsigned)(dst & (BSZ - 1)) << 24) | (unsigned)src;
                atomicAdd(&h[bk[j]], 1);
            }
        }
    }
    __syncthreads();
    if (h[tid]) rbase[tid] = atomicAdd(&gcur[tid], h[tid]);
    h[tid] = 0;
    __syncthreads();
#pragma unroll
    for (int j = 0; j < 16; ++j) {
        if (bk[j] >= 0) {
            int p = atomicAdd(&h[bk[j]], 1);
            binned[rbase[bk[j]] + p] = pk[j];
        }
    }
}

__global__ __launch_bounds__(256) void csr_kernel(const unsigned* __restrict__ binned,
                                                  const int* __restrict__ gbase,
                                                  const float* __restrict__ a_src,
                                                  const float* __restrict__ a_dst,
                                                  int* __restrict__ off,
                                                  int* __restrict__ srt,
                                                  __half* __restrict__ escore,
                                                  int n, int nbuck) {
    __shared__ int cnt[256], buf[256], cur[256];
    __shared__ float adL[BSZ * 4];
    const int tid = threadIdx.x;
    const int b = blockIdx.x;
    const int kb = gbase[b];
    const int ke = gbase[b + 1];
    cnt[tid] = 0;
#pragma unroll
    for (int r = 0; r < 4; ++r) {
        int idx = tid + r * 256;
        int gi = b * (BSZ * 4) + idx;
        adL[idx] = (gi < n * 4) ? a_dst[gi] : 0.f;
    }
    __syncthreads();
    for (int i = kb + tid; i < ke; i += 256)
        atomicAdd(&cnt[binned[i] >> 24], 1);
    __syncthreads();
    int v = cnt[tid];
    buf[tid] = v;
    __syncthreads();
    for (int s = 1; s < 256; s <<= 1) {
        int t = (tid >= s) ? buf[tid - s] : 0;
        __syncthreads();
        buf[tid] += t;
        __syncthreads();
    }
    const int excl = kb + buf[tid] - v;
    const int node = b * BSZ + tid;
    if (node < n) off[node] = excl;
    if (tid == 0 && b == nbuck - 1) off[n] = ke;
    cur[tid] = excl;
    __syncthreads();
    for (int i = kb + tid; i < ke; i += 256) {
        unsigned pv = binned[i];
        int nl = pv >> 24;
        int src = (int)(pv & 0xFFFFFFu);
        int pos = atomicAdd(&cur[nl], 1);
        srt[pos] = src;
        const float4 asv = *(const float4*)&a_src[(size_t)src * 4];
        float t0 = asv.x + adL[nl * 4 + 0]; t0 = (t0 > 0.f) ? t0 : NEG * t0;
        float t1 = asv.y + adL[nl * 4 + 1]; t1 = (t1 > 0.f) ? t1 : NEG * t1;
        float t2 = asv.z + adL[nl * 4 + 2]; t2 = (t2 > 0.f) ? t2 : NEG * t2;
        float t3 = asv.w + adL[nl * 4 + 3]; t3 = (t3 > 0.f) ? t3 : NEG * t3;
        __half2* epr = (__half2*)&escore[(size_t)pos * 4];
        epr[0] = __floats2half2_rn(__expf(t0), __expf(t1));
        epr[1] = __floats2half2_rn(__expf(t2), __expf(t3));
    }
}

// ---------------- aggregate: one wave per dst node, 8-wide batched edge loop ----------------
__global__ __launch_bounds__(256) void agg_kernel(const __half2* __restrict__ xh2,
                                                  const float* __restrict__ a_src,
                                                  const float* __restrict__ a_dst,
                                                  const int* __restrict__ off,
                                                  const int* __restrict__ srt,
                                                  const __half* __restrict__ escore,
                                                  const float* __restrict__ bias,
                                                  float* __restrict__ out, int n) {
    const int gwave = (blockIdx.x * blockDim.x + threadIdx.x) >> 6;
    if (gwave >= n) return;
    const int node = gwave;
    const int lane = threadIdx.x & 63;
    const int h = lane >> 4;

    float e0 = a_src[node * NH + h] + a_dst[node * NH + h];
    e0 = (e0 > 0.f) ? e0 : NEG * e0;
    float g = __expf(e0);
    float2 v = __half22float2(xh2[(size_t)node * 64 + lane]);
    float accx = g * v.x, accy = g * v.y, den = g;

    const int kb = off[node];
    const int ke = off[node + 1];
    int k = kb;
    for (; k + 8 <= ke; k += 8) {
        int s[8];
#pragma unroll
        for (int j = 0; j < 8; ++j) s[j] = srt[k + j];
        float sc[8];
#pragma unroll
        for (int j = 0; j < 8; ++j) sc[j] = __half2float(escore[(size_t)(k + j) * 4 + h]);
        __half2 hv[8];
#pragma unroll
        for (int j = 0; j < 8; ++j) hv[j] = xh2[(size_t)s[j] * 64 + lane];
#pragma unroll
        for (int j = 0; j < 8; ++j) {
            float2 vf = __half22float2(hv[j]);
            accx += sc[j] * vf.x;
            accy += sc[j] * vf.y;
            den  += sc[j];
        }
    }
    for (; k < ke; ++k) {
        const int s = srt[k];
        const float sc = __half2float(escore[(size_t)k * 4 + h]);
        const float2 vf = __half22float2(xh2[(size_t)s * 64 + lane]);
        accx += sc * vf.x;
        accy += sc * vf.y;
        den  += sc;
    }
    const float2 b2 = ((const float2*)bias)[lane];
    const float inv = 1.0f / den;
    float2 o;
    o.x = accx * inv + b2.x;
    o.y = accy * inv + b2.y;
    ((float2*)out)[(size_t)node * 64 + lane] = o;
}

// ---------------- launch ----------------
extern "C" void kernel_launch(void* const* d_in, const int* in_sizes, int n_in,
                              void* d_out, int out_size, void* d_ws, size_t ws_size,
                              hipStream_t stream) {
    if (n_in < 6 || !d_out || !d_ws) return;
    const float* x    = (const float*)d_in[0];
    const int*   ei   = (const int*)d_in[1];
    const float* W    = (const float*)d_in[2];
    const float* attS = (const float*)d_in[3];
    const float* attD = (const float*)d_in[4];
    const float* bias = (const float*)d_in[5];
    float* out = (float*)d_out;

    const int N = in_sizes[0] / DIN;
    const int E = in_sizes[1] / 2;
    if (N <= 0 || E <= 0) return;
    const int NBUCK = (N + BSZ - 1) >> BSH;
    if (NBUCK > 256 || N > (1 << 24)) return;

    char* ws = (char*)d_ws;
    size_t off_b = 0;
    auto carve = [&](size_t bytes) {
        size_t p = off_b;
        off_b = (off_b + bytes + 255) & ~(size_t)255;
        return (void*)(ws + p);
    };
    __half*    xph    = (__half*)carve((size_t)N * HC * 2);
    _Float16*  Wt     = (_Float16*)carve((size_t)HC * DIN * 2);
    float*     a_src  = (float*)carve((size_t)N * NH * 4);
    float*     a_dst  = (float*)carve((size_t)N * NH * 4);
    int*       ghist  = (int*)carve(257 * 4);
    int*       gbase  = (int*)carve(257 * 4);
    int*       gcur   = (int*)carve(257 * 4);
    unsigned*  binned = (unsigned*)carve((size_t)E * 4);
    int*       offp   = (int*)carve((size_t)(N + 1) * 4);
    int*       srt    = (int*)carve((size_t)E * 4);
    __half*    escore = (__half*)carve((size_t)E * NH * 2);
    (void)out_size;
    if (off_b > ws_size) return;

    const int ECH = (E + 4095) / 4096;

    zero_kernel<<<2, 256, 0, stream>>>(ghist, 257);
    wtrans_kernel<<<(DIN * HC) / 256, 256, 0, stream>>>(W, Wt);
    proj_kernel<<<(N + 63) / 64, 256, 0, stream>>>(x, Wt, attS, attD, xph, a_src, a_dst, N);
    hist_kernel<<<ECH, 256, 0, stream>>>(ei, ghist, E, N);
    bscan_kernel<<<1, 256, 0, stream>>>(ghist, gbase, gcur, NBUCK);
    bin_kernel<<<ECH, 256, 0, stream>>>(ei, gcur, binned, E, N);
    csr_kernel<<<NBUCK, 256, 0, stream>>>(binned, gbase, a_src, a_dst, offp, srt,
                                          escore, N, NBUCK);
    agg_kernel<<<(N * 64 + 255) / 256, 256, 0, stream>>>((const __half2*)xph, a_src, a_dst,
                                                         offp, srt, escore, bias, out, N);
}

// Round 10
// 253.337 us; speedup vs baseline: 2.5395x; 1.0361x over previous
//
#include <hip/hip_runtime.h>
#include <hip/hip_fp16.h>

// GATConv: N=50000, E=1600000, DIM_IN=256, HEADS=4, DIM_OUT=32 (HC=128)
// R10: csr_kernel (196 blocks, latency-serial scatter+gather+expf) split:
//   csr -> pure LDS counting sort, stores packed (dst<<16)|src;
//   escore_kernel -> edge-parallel (1.6M threads) score computation.
// proj = f16 MFMA GEMM (R9); agg = fp16 gather, 8-wide (R8).

#define DIN 256
#define HC 128
#define NH 4
#define NEG 0.2f
#define BSH 8
#define BSZ 256

typedef _Float16 half8 __attribute__((ext_vector_type(8)));
typedef _Float16 half2v __attribute__((ext_vector_type(2)));
typedef float f32x4 __attribute__((ext_vector_type(4)));

// ---------------- zero small arrays ----------------
__global__ void zero_kernel(int* __restrict__ p, int n) {
    int i = blockIdx.x * blockDim.x + threadIdx.x;
    if (i < n) p[i] = 0;
}

// ---------------- W transpose + f16 convert: Wt[c][k] ----------------
__global__ __launch_bounds__(256) void wtrans_kernel(const float* __restrict__ W,
                                                     _Float16* __restrict__ Wt) {
    int i = blockIdx.x * 256 + threadIdx.x;
    int k = i >> 7, c = i & 127;
    Wt[c * 256 + k] = (_Float16)W[i];
}

// ---------------- projection via MFMA + fused attention logits ----------------
__global__ __launch_bounds__(256) void proj_kernel(const float* __restrict__ x,
                                                   const _Float16* __restrict__ Wt,
                                                   const float* __restrict__ attS,
                                                   const float* __restrict__ attD,
                                                   __half* __restrict__ xph,
                                                   float* __restrict__ a_src,
                                                   float* __restrict__ a_dst, int n) {
    __shared__ _Float16 smem[8704];
    __shared__ float attSL[128], attDL[128];
    _Float16* xs = smem;                      // [64][40]
    _Float16* Wl = smem + 2560;               // [128][40]
    _Float16* ep = smem;                      // [64][136]

    const int tid  = threadIdx.x;
    const int node0 = blockIdx.x * 64;
    const int wave = tid >> 6;
    const int lane = tid & 63;
    const int l15  = lane & 15;
    const int quad = lane >> 4;

    if (tid < 128) attSL[tid] = attS[tid];
    else           attDL[tid - 128] = attD[tid - 128];

    f32x4 acc[8];
#pragma unroll
    for (int ct = 0; ct < 8; ++ct) acc[ct] = (f32x4){0.f, 0.f, 0.f, 0.f};

    for (int kt = 0; kt < DIN; kt += 32) {
        __syncthreads();
#pragma unroll
        for (int r = 0; r < 4; ++r) {
            int idx = tid + r * 256;
            int row = idx >> 4;
            int kp  = idx & 15;
            int gn = node0 + row;
            float2 xv = make_float2(0.f, 0.f);
            if (gn < n) xv = *(const float2*)&x[(size_t)gn * DIN + kt + kp * 2];
            half2v p; p[0] = (_Float16)xv.x; p[1] = (_Float16)xv.y;
            *(half2v*)&xs[row * 40 + kp * 2] = p;
        }
#pragma unroll
        for (int r = 0; r < 2; ++r) {
            int id = tid + r * 256;
            int c = id >> 2;
            int q = id & 3;
            half8 wv = *(const half8*)&Wt[(size_t)c * 256 + kt + q * 8];
            *(half8*)&Wl[c * 40 + q * 8] = wv;
        }
        __syncthreads();
        half8 af = *(const half8*)&xs[(wave * 16 + l15) * 40 + quad * 8];
#pragma unroll
        for (int ct = 0; ct < 8; ++ct) {
            half8 bf = *(const half8*)&Wl[(ct * 16 + l15) * 40 + quad * 8];
            acc[ct] = __builtin_amdgcn_mfma_f32_16x16x32_f16(af, bf, acc[ct], 0, 0, 0);
        }
    }
    __syncthreads();
#pragma unroll
    for (int ct = 0; ct < 8; ++ct)
#pragma unroll
        for (int r = 0; r < 4; ++r) {
            int row = wave * 16 + quad * 4 + r;
            ep[row * 136 + ct * 16 + l15] = (_Float16)acc[ct][r];
        }
    __syncthreads();
    {
        int row = tid >> 2, ch = tid & 3;
        int node = node0 + row;
        if (node < n) {
            const uint4* s = (const uint4*)&ep[row * 136 + ch * 32];
            uint4* d = (uint4*)&xph[(size_t)node * HC + ch * 32];
            d[0] = s[0]; d[1] = s[1]; d[2] = s[2]; d[3] = s[3];
        }
    }
    {
        int nl = tid >> 2, h = tid & 3;
        int node = node0 + nl;
        if (node < n) {
            float ps = 0.f, pd = 0.f;
            const _Float16* er = &ep[nl * 136 + h * 32];
#pragma unroll
            for (int c = 0; c < 32; ++c) {
                float v = (float)er[c];
                ps += v * attSL[h * 32 + c];
                pd += v * attDL[h * 32 + c];
            }
            a_src[node * NH + h] = ps;
            a_dst[node * NH + h] = pd;
        }
    }
}

// ---------------- CSR build: two-level counting sort ----------------
__global__ __launch_bounds__(256) void hist_kernel(const int* __restrict__ ei,
                                                   int* __restrict__ ghist, int e, int n) {
    __shared__ int h[256];
    const int tid = threadIdx.x;
    h[tid] = 0;
    __syncthreads();
    const int base = blockIdx.x * 4096;
#pragma unroll
    for (int j = 0; j < 16; ++j) {
        int i = base + j * 256 + tid;
        if (i < e) {
            int dst = ei[e + i];
            if ((unsigned)dst < (unsigned)n) atomicAdd(&h[dst >> BSH], 1);
        }
    }
    __syncthreads();
    if (h[tid]) atomicAdd(&ghist[tid], h[tid]);
}

__global__ __launch_bounds__(256) void bscan_kernel(const int* __restrict__ ghist,
                                                    int* __restrict__ gbase,
                                                    int* __restrict__ gcur, int nbuck) {
    __shared__ int buf[256];
    const int tid = threadIdx.x;
    int v = (tid < nbuck) ? ghist[tid] : 0;
    buf[tid] = v;
    __syncthreads();
    for (int s = 1; s < 256; s <<= 1) {
        int t = (tid >= s) ? buf[tid - s] : 0;
        __syncthreads();
        buf[tid] += t;
        __syncthreads();
    }
    int excl = buf[tid] - v;
    if (tid < nbuck) { gbase[tid] = excl; gcur[tid] = excl; }
    if (tid == nbuck - 1) gbase[nbuck] = buf[tid];
}

__global__ __launch_bounds__(256) void bin_kernel(const int* __restrict__ ei,
                                                  int* __restrict__ gcur,
                                                  unsigned* __restrict__ binned,
                                                  int e, int n) {
    __shared__ int h[256];
    __shared__ int rbase[256];
    const int tid = threadIdx.x;
    h[tid] = 0;
    __syncthreads();
    const int base = blockIdx.x * 4096;
    unsigned pk[16];
    int bk[16];
#pragma unroll
    for (int j = 0; j < 16; ++j) {
        int i = base + j * 256 + tid;
        bk[j] = -1;
        if (i < e) {
            int src = ei[i];
            int dst = ei[e + i];
            if ((unsigned)dst < (unsigned)n && (unsigned)src < (unsigned)n) {
                bk[j] = dst >> BSH;
                pk[j] = ((unsigned)(dst & (BSZ - 1)) << 24) | (unsigned)src;
                atomicAdd(&h[bk[j]], 1);
            }
        }
    }
    __syncthreads();
    if (h[tid]) rbase[tid] = atomicAdd(&gcur[tid], h[tid]);
    h[tid] = 0;
    __syncthreads();
#pragma unroll
    for (int j = 0; j < 16; ++j) {
        if (bk[j] >= 0) {
            int p = atomicAdd(&h[bk[j]], 1);
            binned[rbase[bk[j]] + p] = pk[j];
        }
    }
}

// per-bucket LDS counting sort only; srt packed (dst<<16)|src (requires N<=65536)
__global__ __launch_bounds__(256) void csr_kernel(const unsigned* __restrict__ binned,
                                                  const int* __restrict__ gbase,
                                                  int* __restrict__ off,
                                                  unsigned* __restrict__ srt,
                                                  int n, int nbuck) {
    __shared__ int cnt[256], buf[256], cur[256];
    const int tid = threadIdx.x;
    const int b = blockIdx.x;
    const int kb = gbase[b];
    const int ke = gbase[b + 1];
    cnt[tid] = 0;
    __syncthreads();
    for (int i = kb + tid; i < ke; i += 256)
        atomicAdd(&cnt[binned[i] >> 24], 1);
    __syncthreads();
    int v = cnt[tid];
    buf[tid] = v;
    __syncthreads();
    for (int s = 1; s < 256; s <<= 1) {
        int t = (tid >= s) ? buf[tid - s] : 0;
        __syncthreads();
        buf[tid] += t;
        __syncthreads();
    }
    const int excl = kb + buf[tid] - v;
    const int node = b * BSZ + tid;
    if (node < n) off[node] = excl;
    if (tid == 0 && b == nbuck - 1) off[n] = ke;
    cur[tid] = excl;
    __syncthreads();
    const unsigned dbase = (unsigned)(b * BSZ) << 16;
    for (int i = kb + tid; i < ke; i += 256) {
        unsigned pv = binned[i];
        int nl = pv >> 24;
        int pos = atomicAdd(&cur[nl], 1);
        srt[pos] = (dbase + ((unsigned)nl << 16)) | (pv & 0xFFFFu);
    }
}

// edge-parallel score computation: escore[i*4+h] = exp(leaky(a_src[src][h]+a_dst[dst][h]))
__global__ __launch_bounds__(256) void escore_kernel(const unsigned* __restrict__ srt,
                                                     const float* __restrict__ a_src,
                                                     const float* __restrict__ a_dst,
                                                     __half* __restrict__ escore,
                                                     int e, int n) {
    int i = blockIdx.x * 256 + threadIdx.x;
    if (i >= e) return;
    unsigned v = srt[i];
    int src = (int)(v & 0xFFFFu);
    int dst = (int)(v >> 16);
    if (src >= n || dst >= n) return;
    const float4 as = *(const float4*)&a_src[(size_t)src * 4];
    const float4 ad = *(const float4*)&a_dst[(size_t)dst * 4];
    float t0 = as.x + ad.x; t0 = (t0 > 0.f) ? t0 : NEG * t0;
    float t1 = as.y + ad.y; t1 = (t1 > 0.f) ? t1 : NEG * t1;
    float t2 = as.z + ad.z; t2 = (t2 > 0.f) ? t2 : NEG * t2;
    float t3 = as.w + ad.w; t3 = (t3 > 0.f) ? t3 : NEG * t3;
    __half2* ep = (__half2*)&escore[(size_t)i * 4];
    ep[0] = __floats2half2_rn(__expf(t0), __expf(t1));
    ep[1] = __floats2half2_rn(__expf(t2), __expf(t3));
}

// ---------------- aggregate: one wave per dst node, 8-wide batched edge loop ----------------
__global__ __launch_bounds__(256) void agg_kernel(const __half2* __restrict__ xh2,
                                                  const float* __restrict__ a_src,
                                                  const float* __restrict__ a_dst,
                                                  const int* __restrict__ off,
                                                  const unsigned* __restrict__ srt,
                                                  const __half* __restrict__ escore,
                                                  const float* __restrict__ bias,
                                                  float* __restrict__ out, int n) {
    const int gwave = (blockIdx.x * blockDim.x + threadIdx.x) >> 6;
    if (gwave >= n) return;
    const int node = gwave;
    const int lane = threadIdx.x & 63;
    const int h = lane >> 4;

    float e0 = a_src[node * NH + h] + a_dst[node * NH + h];
    e0 = (e0 > 0.f) ? e0 : NEG * e0;
    float g = __expf(e0);
    float2 v = __half22float2(xh2[(size_t)node * 64 + lane]);
    float accx = g * v.x, accy = g * v.y, den = g;

    const int kb = off[node];
    const int ke = off[node + 1];
    int k = kb;
    for (; k + 8 <= ke; k += 8) {
        int s[8];
#pragma unroll
        for (int j = 0; j < 8; ++j) s[j] = (int)(srt[k + j] & 0xFFFFu);
        float sc[8];
#pragma unroll
        for (int j = 0; j < 8; ++j) sc[j] = __half2float(escore[(size_t)(k + j) * 4 + h]);
        __half2 hv[8];
#pragma unroll
        for (int j = 0; j < 8; ++j) hv[j] = xh2[(size_t)s[j] * 64 + lane];
#pragma unroll
        for (int j = 0; j < 8; ++j) {
            float2 vf = __half22float2(hv[j]);
            accx += sc[j] * vf.x;
            accy += sc[j] * vf.y;
            den  += sc[j];
        }
    }
    for (; k < ke; ++k) {
        const int s = (int)(srt[k] & 0xFFFFu);
        const float sc = __half2float(escore[(size_t)k * 4 + h]);
        const float2 vf = __half22float2(xh2[(size_t)s * 64 + lane]);
        accx += sc * vf.x;
        accy += sc * vf.y;
        den  += sc;
    }
    const float2 b2 = ((const float2*)bias)[lane];
    const float inv = 1.0f / den;
    float2 o;
    o.x = accx * inv + b2.x;
    o.y = accy * inv + b2.y;
    ((float2*)out)[(size_t)node * 64 + lane] = o;
}

// ---------------- launch ----------------
extern "C" void kernel_launch(void* const* d_in, const int* in_sizes, int n_in,
                              void* d_out, int out_size, void* d_ws, size_t ws_size,
                              hipStream_t stream) {
    if (n_in < 6 || !d_out || !d_ws) return;
    const float* x    = (const float*)d_in[0];
    const int*   ei   = (const int*)d_in[1];
    const float* W    = (const float*)d_in[2];
    const float* attS = (const float*)d_in[3];
    const float* attD = (const float*)d_in[4];
    const float* bias = (const float*)d_in[5];
    float* out = (float*)d_out;

    const int N = in_sizes[0] / DIN;
    const int E = in_sizes[1] / 2;
    if (N <= 0 || E <= 0) return;
    const int NBUCK = (N + BSZ - 1) >> BSH;
    if (NBUCK > 256 || N > 65536) return;   // dst<<16 packing requires N<=65536

    char* ws = (char*)d_ws;
    size_t off_b = 0;
    auto carve = [&](size_t bytes) {
        size_t p = off_b;
        off_b = (off_b + bytes + 255) & ~(size_t)255;
        return (void*)(ws + p);
    };
    __half*    xph    = (__half*)carve((size_t)N * HC * 2);
    _Float16*  Wt     = (_Float16*)carve((size_t)HC * DIN * 2);
    float*     a_src  = (float*)carve((size_t)N * NH * 4);
    float*     a_dst  = (float*)carve((size_t)N * NH * 4);
    int*       ghist  = (int*)carve(257 * 4);
    int*       gbase  = (int*)carve(257 * 4);
    int*       gcur   = (int*)carve(257 * 4);
    unsigned*  binned = (unsigned*)carve((size_t)E * 4);
    int*       offp   = (int*)carve((size_t)(N + 1) * 4);
    unsigned*  srt    = (unsigned*)carve((size_t)E * 4);
    __half*    escore = (__half*)carve((size_t)E * NH * 2);
    (void)out_size;
    if (off_b > ws_size) return;

    const int ECH = (E + 4095) / 4096;

    zero_kernel<<<2, 256, 0, stream>>>(ghist, 257);
    wtrans_kernel<<<(DIN * HC) / 256, 256, 0, stream>>>(W, Wt);
    proj_kernel<<<(N + 63) / 64, 256, 0, stream>>>(x, Wt, attS, attD, xph, a_src, a_dst, N);
    hist_kernel<<<ECH, 256, 0, stream>>>(ei, ghist, E, N);
    bscan_kernel<<<1, 256, 0, stream>>>(ghist, gbase, gcur, NBUCK);
    bin_kernel<<<ECH, 256, 0, stream>>>(ei, gcur, binned, E, N);
    csr_kernel<<<NBUCK, 256, 0, stream>>>(binned, gbase, offp, srt, N, NBUCK);
    escore_kernel<<<(E + 255) / 256, 256, 0, stream>>>(srt, a_src, a_dst, escore, E, N);
    agg_kernel<<<(N * 64 + 255) / 256, 256, 0, stream>>>((const __half2*)xph, a_src, a_dst,
                                                         offp, srt, escore, bias, out, N);
}